// Round 8
// baseline (778.454 us; speedup 1.0000x reference)
//
#include <hip/hip_runtime.h>
#include <hip/hip_bf16.h>
#include <math.h>

#define EPS_ 1e-5f
constexpr int B_ = 4, NA = 64, T_ = 128, D_ = 128, H_ = 8, L_ = 3, DFF = 512, E_ = 65536;
constexpr int DH = D_ / H_;        // 16
constexpr int NN = T_ * NA;        // 8192
constexpr int NTOT = B_ * NA * T_; // 32768
constexpr int QLD = 384;           // packed QKV row stride

typedef __bf16 bf16x8 __attribute__((ext_vector_type(8)));
typedef float f32x4 __attribute__((ext_vector_type(4)));

// ---------------- embed: x = hist@W + b ; e = x + posenc ----------------
__global__ __launch_bounds__(256) void embed_kernel(
    const float* __restrict__ hist, const float* __restrict__ w,
    const float* __restrict__ b, float* __restrict__ x, float* __restrict__ e) {
  int idx = blockIdx.x * 256 + threadIdx.x;
  if (idx >= NTOT * D_) return;
  int d = idx & (D_ - 1);
  int r = idx >> 7;
  int t = r & (T_ - 1);
  const float* hp = hist + (size_t)r * 3;
  float acc = b[d];
  acc += hp[0] * w[0 * D_ + d];
  acc += hp[1] * w[1 * D_ + d];
  acc += hp[2] * w[2 * D_ + d];
  x[idx] = acc;
  int p = d >> 1;
  float ang = (float)t * expf(-logf(10000.f) * (2.f * (float)p) / (float)D_);
  float pe = (d & 1) ? cosf(ang) : sinf(ang);
  e[idx] = acc + pe;
}

// ---------------- weight split+transpose into [N][K] bf16 hi/lo, QKV packed ----------------
__global__ __launch_bounds__(256) void convert_weights(
    const float* __restrict__ wq, const float* __restrict__ wk,
    const float* __restrict__ wv, const float* __restrict__ wo,
    const float* __restrict__ w1, const float* __restrict__ w2,
    __bf16* __restrict__ hi, __bf16* __restrict__ lo) {
  const int LW = 196608;
  int idx = blockIdx.x * 256 + threadIdx.x;
  if (idx >= L_ * LW) return;
  int l = idx / LW;
  int rem = idx - l * LW;
  float src;
  int dst;
  if (rem < 49152) {
    int n = rem >> 7, k = rem & 127; // n in [0,384)
    int which = n >> 7, nl = n & 127;
    const float* W = (which == 0) ? wq : (which == 1) ? wk : wv;
    src = W[(size_t)l * 16384 + k * 128 + nl];
    dst = l * LW + n * 128 + k;
  } else if (rem < 65536) {
    int r2 = rem - 49152;
    int n = r2 >> 7, k = r2 & 127;
    src = wo[(size_t)l * 16384 + k * 128 + n];
    dst = l * LW + 49152 + n * 128 + k;
  } else if (rem < 131072) {
    int r2 = rem - 65536;
    int n = r2 >> 7, k = r2 & 127; // n in [0,512)
    src = w1[(size_t)l * 65536 + k * 512 + n];
    dst = l * LW + 65536 + n * 128 + k;
  } else {
    int r2 = rem - 131072;
    int n = r2 >> 9, k = r2 & 511; // n in [0,128), k in [0,512)
    src = w2[(size_t)l * 65536 + k * 128 + n];
    dst = l * LW + 131072 + n * 512 + k;
  }
  __bf16 h = (__bf16)src;
  hi[dst] = h;
  lo[dst] = (__bf16)(src - (float)h);
}

// ---------------- pack QKV biases: pb[l][384] = bq|bk|bv ----------------
__global__ __launch_bounds__(256) void bias_pack(
    const float* __restrict__ bq, const float* __restrict__ bk,
    const float* __restrict__ bv, float* __restrict__ pb) {
  int idx = blockIdx.x * 256 + threadIdx.x;
  if (idx >= L_ * QLD) return;
  int l = idx / QLD, n = idx - l * QLD;
  int which = n >> 7, nl = n & 127;
  const float* src = (which == 0) ? bq : (which == 1) ? bk : bv;
  pb[idx] = src[l * 128 + nl];
}

// ---------------- MFMA GEMM, 128x128 block tile; EPI 0=bias 1=bias+relu ----------------
template <int EPI>
__global__ __launch_bounds__(256) void gemm_mfma(
    const float* __restrict__ A, int lda,
    const __bf16* __restrict__ Whi, const __bf16* __restrict__ Wlo,
    const float* __restrict__ bias,
    float* __restrict__ C, int ldc, int M, int N, int K) {
  const int wave = threadIdx.x >> 6;
  const int lane = threadIdx.x & 63;
  const int m16 = lane & 15;
  const int quad = lane >> 4;
  const int wrow = wave >> 1, wcol = wave & 1;
  const int row0 = blockIdx.y * 128 + wrow * 64;
  const int col0 = blockIdx.x * 128 + wcol * 64;

  f32x4 acc[4][4] = {};
  for (int k0 = 0; k0 < K; k0 += 32) {
    bf16x8 ahi[4], alo[4];
#pragma unroll
    for (int mf = 0; mf < 4; ++mf) {
      const float* ap = A + (size_t)(row0 + mf * 16 + m16) * lda + k0 + quad * 8;
      float4 x0 = *(const float4*)ap;
      float4 x1 = *(const float4*)(ap + 4);
      float xv[8] = {x0.x, x0.y, x0.z, x0.w, x1.x, x1.y, x1.z, x1.w};
#pragma unroll
      for (int j = 0; j < 8; ++j) {
        __bf16 h = (__bf16)xv[j];
        ahi[mf][j] = h;
        alo[mf][j] = (__bf16)(xv[j] - (float)h);
      }
    }
    bf16x8 bhi[4], blo[4];
#pragma unroll
    for (int nf = 0; nf < 4; ++nf) {
      size_t off = (size_t)(col0 + nf * 16 + m16) * K + k0 + quad * 8;
      bhi[nf] = *(const bf16x8*)(Whi + off);
      blo[nf] = *(const bf16x8*)(Wlo + off);
    }
#pragma unroll
    for (int mf = 0; mf < 4; ++mf)
#pragma unroll
      for (int nf = 0; nf < 4; ++nf) {
        acc[mf][nf] = __builtin_amdgcn_mfma_f32_16x16x32_bf16(ahi[mf], bhi[nf], acc[mf][nf], 0, 0, 0);
        acc[mf][nf] = __builtin_amdgcn_mfma_f32_16x16x32_bf16(ahi[mf], blo[nf], acc[mf][nf], 0, 0, 0);
        acc[mf][nf] = __builtin_amdgcn_mfma_f32_16x16x32_bf16(alo[mf], bhi[nf], acc[mf][nf], 0, 0, 0);
      }
  }
#pragma unroll
  for (int mf = 0; mf < 4; ++mf)
#pragma unroll
    for (int nf = 0; nf < 4; ++nf) {
      int c = col0 + nf * 16 + m16;
      float bj = bias[c];
#pragma unroll
      for (int reg = 0; reg < 4; ++reg) {
        int r = row0 + mf * 16 + quad * 4 + reg;
        float v = acc[mf][nf][reg] + bj;
        if (EPI == 1) v = fmaxf(v, 0.f);
        C[(size_t)r * ldc + c] = v;
      }
    }
}

// ---------------- GEMM + bias + residual + LayerNorm, N==128, all in-wave ----------------
// One wave owns 16 rows x 128 cols (acc[8]); block = 4 waves = 64 rows; grid M/64.
// Row reduction: in-lane over 8 col-tiles + shfl_xor{1,2,4,8} within the quad's
// 16 lanes (which hold that row's 16 cols per tile). No LDS, no barrier.
__global__ __launch_bounds__(256) void gemm_ln(
    const float* __restrict__ A, int lda,
    const __bf16* __restrict__ Whi, const __bf16* __restrict__ Wlo,
    const float* __restrict__ bias, const float* __restrict__ resid,
    const float* __restrict__ lng, const float* __restrict__ lnb,
    float* __restrict__ C, int K) {
  const int wave = threadIdx.x >> 6;
  const int lane = threadIdx.x & 63;
  const int m16 = lane & 15;
  const int quad = lane >> 4;
  const int row0 = blockIdx.x * 64 + wave * 16;

  f32x4 acc[8] = {};
  for (int k0 = 0; k0 < K; k0 += 32) {
    bf16x8 ahi, alo;
    {
      const float* ap = A + (size_t)(row0 + m16) * lda + k0 + quad * 8;
      float4 x0 = *(const float4*)ap;
      float4 x1 = *(const float4*)(ap + 4);
      float xv[8] = {x0.x, x0.y, x0.z, x0.w, x1.x, x1.y, x1.z, x1.w};
#pragma unroll
      for (int j = 0; j < 8; ++j) {
        __bf16 h = (__bf16)xv[j];
        ahi[j] = h;
        alo[j] = (__bf16)(xv[j] - (float)h);
      }
    }
#pragma unroll
    for (int nf = 0; nf < 8; ++nf) {
      size_t off = (size_t)(nf * 16 + m16) * K + k0 + quad * 8;
      bf16x8 bhi = *(const bf16x8*)(Whi + off);
      bf16x8 blo = *(const bf16x8*)(Wlo + off);
      acc[nf] = __builtin_amdgcn_mfma_f32_16x16x32_bf16(ahi, bhi, acc[nf], 0, 0, 0);
      acc[nf] = __builtin_amdgcn_mfma_f32_16x16x32_bf16(ahi, blo, acc[nf], 0, 0, 0);
      acc[nf] = __builtin_amdgcn_mfma_f32_16x16x32_bf16(alo, bhi, acc[nf], 0, 0, 0);
    }
  }
#pragma unroll
  for (int reg = 0; reg < 4; ++reg) {
    int r = row0 + quad * 4 + reg;
    float s = 0.f, qq = 0.f;
#pragma unroll
    for (int nf = 0; nf < 8; ++nf) {
      int c = nf * 16 + m16;
      float v = acc[nf][reg] + bias[c] + resid[(size_t)r * 128 + c];
      acc[nf][reg] = v;
      s += v;
      qq += v * v;
    }
#pragma unroll
    for (int off = 1; off < 16; off <<= 1) {
      s += __shfl_xor(s, off, 64);
      qq += __shfl_xor(qq, off, 64);
    }
    float mean = s * (1.f / 128.f);
    float var = qq * (1.f / 128.f) - mean * mean;
    float rstd = rsqrtf(var + EPS_);
#pragma unroll
    for (int nf = 0; nf < 8; ++nf) {
      int c = nf * 16 + m16;
      C[(size_t)r * 128 + c] = (acc[nf][reg] - mean) * rstd * lng[c] + lnb[c];
    }
  }
}

// ---------------- MFMA attention on packed QKV; O overwrites the V slice ----------------
__global__ __launch_bounds__(256) void attn_mfma(float* __restrict__ qkv) {
  const int h = blockIdx.x & (H_ - 1);
  const int bn = blockIdx.x >> 3;
  const int wave = threadIdx.x >> 6;
  const int lane = threadIdx.x & 63;
  const int m16 = lane & 15;
  const int quad = lane >> 4;
  const int row0 = wave * 32;
  const float* Qb = qkv + (size_t)bn * T_ * QLD + h * DH;
  const float* Kb = Qb + 128;
  const float* Vb = Qb + 256;
  float* Ob = (float*)Vb;

  __shared__ __bf16 Plds[4][32][136];

  bf16x8 qhi[2], qlo[2];
#pragma unroll
  for (int mf = 0; mf < 2; ++mf) {
    if (quad < 2) {
      const float* ap = Qb + (size_t)(row0 + mf * 16 + m16) * QLD + quad * 8;
      float4 x0 = *(const float4*)ap;
      float4 x1 = *(const float4*)(ap + 4);
      float xv[8] = {x0.x, x0.y, x0.z, x0.w, x1.x, x1.y, x1.z, x1.w};
#pragma unroll
      for (int j = 0; j < 8; ++j) {
        __bf16 hh = (__bf16)xv[j];
        qhi[mf][j] = hh;
        qlo[mf][j] = (__bf16)(xv[j] - (float)hh);
      }
    } else {
#pragma unroll
      for (int j = 0; j < 8; ++j) { qhi[mf][j] = (__bf16)0.f; qlo[mf][j] = (__bf16)0.f; }
    }
  }

  f32x4 acc[2][8] = {};
#pragma unroll
  for (int nf = 0; nf < 8; ++nf) {
    bf16x8 khi, klo;
    if (quad < 2) {
      const float* kp = Kb + (size_t)(nf * 16 + m16) * QLD + quad * 8;
      float4 x0 = *(const float4*)kp;
      float4 x1 = *(const float4*)(kp + 4);
      float xv[8] = {x0.x, x0.y, x0.z, x0.w, x1.x, x1.y, x1.z, x1.w};
#pragma unroll
      for (int j = 0; j < 8; ++j) {
        __bf16 hh = (__bf16)xv[j];
        khi[j] = hh;
        klo[j] = (__bf16)(xv[j] - (float)hh);
      }
    } else {
#pragma unroll
      for (int j = 0; j < 8; ++j) { khi[j] = (__bf16)0.f; klo[j] = (__bf16)0.f; }
    }
#pragma unroll
    for (int mf = 0; mf < 2; ++mf) {
      acc[mf][nf] = __builtin_amdgcn_mfma_f32_16x16x32_bf16(qhi[mf], khi, acc[mf][nf], 0, 0, 0);
      acc[mf][nf] = __builtin_amdgcn_mfma_f32_16x16x32_bf16(qhi[mf], klo, acc[mf][nf], 0, 0, 0);
      acc[mf][nf] = __builtin_amdgcn_mfma_f32_16x16x32_bf16(qlo[mf], khi, acc[mf][nf], 0, 0, 0);
    }
  }

  const float scale = 0.25f;
#pragma unroll
  for (int mf = 0; mf < 2; ++mf)
#pragma unroll
    for (int reg = 0; reg < 4; ++reg) {
      float mx = -1e30f;
#pragma unroll
      for (int nf = 0; nf < 8; ++nf) mx = fmaxf(mx, acc[mf][nf][reg]);
#pragma unroll
      for (int off = 1; off < 16; off <<= 1) mx = fmaxf(mx, __shfl_xor(mx, off, 64));
      float sum = 0.f;
#pragma unroll
      for (int nf = 0; nf < 8; ++nf) {
        float e = __expf((acc[mf][nf][reg] - mx) * scale);
        acc[mf][nf][reg] = e;
        sum += e;
      }
#pragma unroll
      for (int off = 1; off < 16; off <<= 1) sum += __shfl_xor(sum, off, 64);
      float inv = 1.f / sum;
#pragma unroll
      for (int nf = 0; nf < 8; ++nf) acc[mf][nf][reg] *= inv;
    }

#pragma unroll
  for (int mf = 0; mf < 2; ++mf)
#pragma unroll
    for (int nf = 0; nf < 8; ++nf)
#pragma unroll
      for (int reg = 0; reg < 4; ++reg)
        Plds[wave][mf * 16 + quad * 4 + reg][nf * 16 + m16] = (__bf16)acc[mf][nf][reg];

  f32x4 oacc[2] = {};
#pragma unroll
  for (int kc = 0; kc < 4; ++kc) {
    bf16x8 pa0 = *(const bf16x8*)&Plds[wave][m16][kc * 32 + quad * 8];
    bf16x8 pa1 = *(const bf16x8*)&Plds[wave][16 + m16][kc * 32 + quad * 8];
    bf16x8 vhi, vlo;
#pragma unroll
    for (int j = 0; j < 8; ++j) {
      float x = Vb[(size_t)(kc * 32 + quad * 8 + j) * QLD + m16];
      __bf16 hh = (__bf16)x;
      vhi[j] = hh;
      vlo[j] = (__bf16)(x - (float)hh);
    }
    oacc[0] = __builtin_amdgcn_mfma_f32_16x16x32_bf16(pa0, vhi, oacc[0], 0, 0, 0);
    oacc[0] = __builtin_amdgcn_mfma_f32_16x16x32_bf16(pa0, vlo, oacc[0], 0, 0, 0);
    oacc[1] = __builtin_amdgcn_mfma_f32_16x16x32_bf16(pa1, vhi, oacc[1], 0, 0, 0);
    oacc[1] = __builtin_amdgcn_mfma_f32_16x16x32_bf16(pa1, vlo, oacc[1], 0, 0, 0);
  }

  __syncthreads();
#pragma unroll
  for (int mf = 0; mf < 2; ++mf)
#pragma unroll
    for (int reg = 0; reg < 4; ++reg) {
      int r = row0 + mf * 16 + quad * 4 + reg;
      Ob[(size_t)r * QLD + m16] = oacc[mf][reg];
    }
}

// ---------------- gating dot ----------------
__global__ __launch_bounds__(256) void sdot_kernel(
    const float* __restrict__ e, const float* __restrict__ x, float* __restrict__ s) {
  int r = blockIdx.x * 4 + (threadIdx.x >> 6);
  int lane = threadIdx.x & 63;
  const float* ep = e + (size_t)r * D_;
  const float* xp = x + (size_t)r * D_;
  float acc = ep[lane] * xp[lane] + ep[lane + 64] * xp[lane + 64];
#pragma unroll
  for (int off = 32; off; off >>= 1) acc += __shfl_down(acc, off, 64);
  if (lane == 0) {
    int t = r & (T_ - 1);
    int bn = r >> 7;
    int n = bn & (NA - 1);
    int b = bn >> 6;
    s[(size_t)b * NN + t * NA + n] = acc;
  }
}

// ---------------- edge scatter ----------------
__global__ __launch_bounds__(256) void scatter_kernel(
    const float* __restrict__ s, const int* __restrict__ ei,
    const float* __restrict__ ew, float* __restrict__ g) {
  int idx = blockIdx.x * 256 + threadIdx.x;
  if (idx >= B_ * E_) return;
  int b = idx >> 16;
  int e = idx & (E_ - 1);
  int src = ei[(size_t)b * 2 * E_ + e];
  int dst = ei[(size_t)b * 2 * E_ + E_ + e];
  float w = ew[(size_t)b * E_ + e];
  atomicAdd(&g[(size_t)b * NN + dst], w * s[(size_t)b * NN + src]);
}

// ---------------- partial sums for global mean/var ----------------
__global__ __launch_bounds__(256) void stats_partial(
    const float* __restrict__ g, float* __restrict__ st) {
  int i = blockIdx.x * 256 + threadIdx.x;
  float v = g[i];
  float sum = v, sq = v * v;
#pragma unroll
  for (int off = 32; off; off >>= 1) {
    sum += __shfl_down(sum, off, 64);
    sq += __shfl_down(sq, off, 64);
  }
  __shared__ float s1[4], s2[4];
  int w = threadIdx.x >> 6;
  if ((threadIdx.x & 63) == 0) { s1[w] = sum; s2[w] = sq; }
  __syncthreads();
  if (threadIdx.x == 0) {
    atomicAdd(&st[0], s1[0] + s1[1] + s1[2] + s1[3]);
    atomicAdd(&st[1], s2[0] + s2[1] + s2[2] + s2[3]);
  }
}

// ---------------- final (fp32 out) ----------------
__global__ __launch_bounds__(256) void final_kernel(
    const float* __restrict__ g, const float* __restrict__ st,
    const float* __restrict__ bng, const float* __restrict__ bnb,
    const float* __restrict__ lw, const float* __restrict__ lb,
    float* __restrict__ out) {
  int idx = blockIdx.x * 256 + threadIdx.x;
  if (idx >= NTOT * D_) return;
  int d = idx & (D_ - 1);
  int r = idx >> 7;
  int t = r & (T_ - 1);
  int bn = r >> 7;
  int n = bn & (NA - 1);
  int b = bn >> 6;
  const float invn = 1.f / (float)(B_ * NN);
  float m = st[0] * invn;
  float var = st[1] * invn - m * m;
  float rs = rsqrtf(var + EPS_);
  float gv = g[(size_t)b * NN + t * NA + n];
  float val = (gv - m) * rs * bng[0] + bnb[0];
  out[idx] = val * lw[d] + lb[d];
}

extern "C" void kernel_launch(void* const* d_in, const int* in_sizes, int n_in,
                              void* d_out, int out_size, void* d_ws, size_t ws_size,
                              hipStream_t stream) {
  const float* hist = (const float*)d_in[0];
  const int* eidx = (const int*)d_in[1];
  const float* ew = (const float*)d_in[2];
  const float* hw = (const float*)d_in[3];
  const float* hb = (const float*)d_in[4];
  const float* wq = (const float*)d_in[5];
  const float* bq = (const float*)d_in[6];
  const float* wk = (const float*)d_in[7];
  const float* bk = (const float*)d_in[8];
  const float* wv = (const float*)d_in[9];
  const float* bv = (const float*)d_in[10];
  const float* wo = (const float*)d_in[11];
  const float* bo = (const float*)d_in[12];
  const float* ln1g = (const float*)d_in[13];
  const float* ln1b = (const float*)d_in[14];
  const float* w1 = (const float*)d_in[15];
  const float* b1 = (const float*)d_in[16];
  const float* w2 = (const float*)d_in[17];
  const float* b2 = (const float*)d_in[18];
  const float* ln2g = (const float*)d_in[19];
  const float* ln2b = (const float*)d_in[20];
  const float* bng = (const float*)d_in[21];
  const float* bnb = (const float*)d_in[22];
  const float* lgw = (const float*)d_in[23];
  const float* lgb = (const float*)d_in[24];
  float* out = (float*)d_out;

  float* ws = (float*)d_ws;
  const size_t NE = (size_t)NTOT * D_;
  float* bx = ws + 0 * NE;
  float* be = ws + 1 * NE;
  float* h1 = ws + 2 * NE;
  float* qkv = ws + 3 * NE;   // 3NE, [row][384]
  float* ffmid = ws + 3 * NE; // 4NE, overlaps dead qkv
  float* bs_ = ws + 7 * NE;
  float* bg_ = bs_ + NTOT;
  float* bst = bg_ + NTOT;
  float* pbias = bst + 2;
  const int LW = 196608;
  __bf16* whiB = (__bf16*)(pbias + L_ * QLD);
  __bf16* wloB = whiB + (size_t)L_ * LW;

  convert_weights<<<(L_ * LW + 255) / 256, 256, 0, stream>>>(
      wq, wk, wv, wo, w1, w2, whiB, wloB);
  bias_pack<<<(L_ * QLD + 255) / 256, 256, 0, stream>>>(bq, bk, bv, pbias);
  embed_kernel<<<(NTOT * D_) / 256, 256, 0, stream>>>(hist, hw, hb, bx, be);

  for (int l = 0; l < L_; ++l) {
    const __bf16* hiL = whiB + (size_t)l * LW;
    const __bf16* loL = wloB + (size_t)l * LW;
    // QKV: one N=384 GEMM into packed [row][384]
    gemm_mfma<0><<<dim3(3, NTOT / 128), 256, 0, stream>>>(
        be, 128, hiL, loL, pbias + l * QLD, qkv, QLD, NTOT, QLD, 128);
    attn_mfma<<<B_ * NA * H_, 256, 0, stream>>>(qkv);
    // O-proj + residual(be) + LN1 -> h1   (wave-per-16-rows, in-wave LN)
    gemm_ln<<<NTOT / 64, 256, 0, stream>>>(
        qkv + 256, QLD, hiL + 49152, loL + 49152, bo + l * D_, be,
        ln1g + l * D_, ln1b + l * D_, h1, 128);
    // FF1 (relu) -> ffmid
    gemm_mfma<1><<<dim3(4, NTOT / 128), 256, 0, stream>>>(
        h1, 128, hiL + 65536, loL + 65536, b1 + l * DFF, ffmid, 512, NTOT, DFF, 128);
    // FF2 + residual(h1) + LN2 -> be
    gemm_ln<<<NTOT / 64, 256, 0, stream>>>(
        ffmid, 512, hiL + 131072, loL + 131072, b2 + l * D_, h1,
        ln2g + l * D_, ln2b + l * D_, be, DFF);
  }

  sdot_kernel<<<NTOT / 4, 256, 0, stream>>>(be, bx, bs_);
  hipMemsetAsync(bg_, 0, ((size_t)B_ * NN + 2) * sizeof(float), stream);
  scatter_kernel<<<(B_ * E_) / 256, 256, 0, stream>>>(bs_, eidx, ew, bg_);
  stats_partial<<<(B_ * NN) / 256, 256, 0, stream>>>(bg_, bst);
  final_kernel<<<(NTOT * D_) / 256, 256, 0, stream>>>(bg_, bst, bng, bnb, lgw, lgb, out);
}

// Round 9
// 759.319 us; speedup vs baseline: 1.0252x; 1.0252x over previous
//
#include <hip/hip_runtime.h>
#include <hip/hip_bf16.h>
#include <math.h>

#define EPS_ 1e-5f
constexpr int B_ = 4, NA = 64, T_ = 128, D_ = 128, H_ = 8, L_ = 3, DFF = 512, E_ = 65536;
constexpr int DH = D_ / H_;        // 16
constexpr int NN = T_ * NA;        // 8192
constexpr int NTOT = B_ * NA * T_; // 32768
constexpr int QLD = 384;           // packed QKV row stride

typedef __bf16 bf16x8 __attribute__((ext_vector_type(8)));
typedef float f32x4 __attribute__((ext_vector_type(4)));

// ---------------- embed: x = hist@W + b ; e = x + posenc ----------------
__global__ __launch_bounds__(256) void embed_kernel(
    const float* __restrict__ hist, const float* __restrict__ w,
    const float* __restrict__ b, float* __restrict__ x, float* __restrict__ e) {
  int idx = blockIdx.x * 256 + threadIdx.x;
  if (idx >= NTOT * D_) return;
  int d = idx & (D_ - 1);
  int r = idx >> 7;
  int t = r & (T_ - 1);
  const float* hp = hist + (size_t)r * 3;
  float acc = b[d];
  acc += hp[0] * w[0 * D_ + d];
  acc += hp[1] * w[1 * D_ + d];
  acc += hp[2] * w[2 * D_ + d];
  x[idx] = acc;
  int p = d >> 1;
  float ang = (float)t * expf(-logf(10000.f) * (2.f * (float)p) / (float)D_);
  float pe = (d & 1) ? cosf(ang) : sinf(ang);
  e[idx] = acc + pe;
}

// ---------------- weight split+transpose into [N][K] bf16 hi/lo, QKV packed ----------------
__global__ __launch_bounds__(256) void convert_weights(
    const float* __restrict__ wq, const float* __restrict__ wk,
    const float* __restrict__ wv, const float* __restrict__ wo,
    const float* __restrict__ w1, const float* __restrict__ w2,
    __bf16* __restrict__ hi, __bf16* __restrict__ lo) {
  const int LW = 196608;
  int idx = blockIdx.x * 256 + threadIdx.x;
  if (idx >= L_ * LW) return;
  int l = idx / LW;
  int rem = idx - l * LW;
  float src;
  int dst;
  if (rem < 49152) {
    int n = rem >> 7, k = rem & 127; // n in [0,384)
    int which = n >> 7, nl = n & 127;
    const float* W = (which == 0) ? wq : (which == 1) ? wk : wv;
    src = W[(size_t)l * 16384 + k * 128 + nl];
    dst = l * LW + n * 128 + k;
  } else if (rem < 65536) {
    int r2 = rem - 49152;
    int n = r2 >> 7, k = r2 & 127;
    src = wo[(size_t)l * 16384 + k * 128 + n];
    dst = l * LW + 49152 + n * 128 + k;
  } else if (rem < 131072) {
    int r2 = rem - 65536;
    int n = r2 >> 7, k = r2 & 127; // n in [0,512)
    src = w1[(size_t)l * 65536 + k * 512 + n];
    dst = l * LW + 65536 + n * 128 + k;
  } else {
    int r2 = rem - 131072;
    int n = r2 >> 9, k = r2 & 511; // n in [0,128), k in [0,512)
    src = w2[(size_t)l * 65536 + k * 128 + n];
    dst = l * LW + 131072 + n * 512 + k;
  }
  __bf16 h = (__bf16)src;
  hi[dst] = h;
  lo[dst] = (__bf16)(src - (float)h);
}

// ---------------- pack QKV biases: pb[l][384] = bq|bk|bv ----------------
__global__ __launch_bounds__(256) void bias_pack(
    const float* __restrict__ bq, const float* __restrict__ bk,
    const float* __restrict__ bv, float* __restrict__ pb) {
  int idx = blockIdx.x * 256 + threadIdx.x;
  if (idx >= L_ * QLD) return;
  int l = idx / QLD, n = idx - l * QLD;
  int which = n >> 7, nl = n & 127;
  const float* src = (which == 0) ? bq : (which == 1) ? bk : bv;
  pb[idx] = src[l * 128 + nl];
}

// ---------------- MFMA GEMM v2: block 64 rows x 128 cols, 4 waves 2x2 (wave 32x64) ----------------
// EPI: 0=bias, 1=bias+relu, 2=bias+resid+LayerNorm (requires total N==128, gridDim.x==1).
// fp32-grade via hi/lo split. B-reuse 2 (mf), A-reuse 2 (nf); grid.y = M/64.
template <int EPI>
__global__ __launch_bounds__(256) void gemm2(
    const float* __restrict__ A, int lda,
    const __bf16* __restrict__ Whi, const __bf16* __restrict__ Wlo,
    const float* __restrict__ bias, const float* __restrict__ resid,
    const float* __restrict__ lng, const float* __restrict__ lnb,
    float* __restrict__ C, int ldc, int K) {
  const int wave = threadIdx.x >> 6;
  const int lane = threadIdx.x & 63;
  const int m16 = lane & 15;
  const int quad = lane >> 4;
  const int wrow = wave >> 1, wcol = wave & 1;
  const int row0 = blockIdx.y * 64 + wrow * 32;
  const int col0 = blockIdx.x * 128 + wcol * 64;

  f32x4 acc[2][4] = {};
  for (int k0 = 0; k0 < K; k0 += 32) {
    bf16x8 ahi[2], alo[2];
#pragma unroll
    for (int mf = 0; mf < 2; ++mf) {
      const float* ap = A + (size_t)(row0 + mf * 16 + m16) * lda + k0 + quad * 8;
      float4 x0 = *(const float4*)ap;
      float4 x1 = *(const float4*)(ap + 4);
      float xv[8] = {x0.x, x0.y, x0.z, x0.w, x1.x, x1.y, x1.z, x1.w};
#pragma unroll
      for (int j = 0; j < 8; ++j) {
        __bf16 h = (__bf16)xv[j];
        ahi[mf][j] = h;
        alo[mf][j] = (__bf16)(xv[j] - (float)h);
      }
    }
    bf16x8 bhi[4], blo[4];
#pragma unroll
    for (int nf = 0; nf < 4; ++nf) {
      size_t off = (size_t)(col0 + nf * 16 + m16) * K + k0 + quad * 8;
      bhi[nf] = *(const bf16x8*)(Whi + off);
      blo[nf] = *(const bf16x8*)(Wlo + off);
    }
#pragma unroll
    for (int mf = 0; mf < 2; ++mf)
#pragma unroll
      for (int nf = 0; nf < 4; ++nf) {
        acc[mf][nf] = __builtin_amdgcn_mfma_f32_16x16x32_bf16(ahi[mf], bhi[nf], acc[mf][nf], 0, 0, 0);
        acc[mf][nf] = __builtin_amdgcn_mfma_f32_16x16x32_bf16(ahi[mf], blo[nf], acc[mf][nf], 0, 0, 0);
        acc[mf][nf] = __builtin_amdgcn_mfma_f32_16x16x32_bf16(alo[mf], bhi[nf], acc[mf][nf], 0, 0, 0);
      }
  }

  if (EPI < 2) {
#pragma unroll
    for (int mf = 0; mf < 2; ++mf)
#pragma unroll
      for (int nf = 0; nf < 4; ++nf) {
        int c = col0 + nf * 16 + m16;
        float bj = bias[c];
#pragma unroll
        for (int reg = 0; reg < 4; ++reg) {
          int r = row0 + mf * 16 + quad * 4 + reg;
          float v = acc[mf][nf][reg] + bj;
          if (EPI == 1) v = fmaxf(v, 0.f);
          C[(size_t)r * ldc + c] = v;
        }
      }
  } else {
    // N==128 total: each row's cols split across wcol pair -> LDS reduce, 1 barrier.
    __shared__ float rs[64][2], rq[64][2];
#pragma unroll
    for (int mf = 0; mf < 2; ++mf)
#pragma unroll
      for (int reg = 0; reg < 4; ++reg) {
        int lr = wrow * 32 + mf * 16 + quad * 4 + reg; // local row [0,64)
        int gr = blockIdx.y * 64 + lr;
        float s = 0.f, qq = 0.f;
#pragma unroll
        for (int nf = 0; nf < 4; ++nf) {
          int c = wcol * 64 + nf * 16 + m16;
          float v = acc[mf][nf][reg] + bias[c] + resid[(size_t)gr * 128 + c];
          acc[mf][nf][reg] = v;
          s += v;
          qq += v * v;
        }
#pragma unroll
        for (int off = 1; off < 16; off <<= 1) {
          s += __shfl_xor(s, off, 64);
          qq += __shfl_xor(qq, off, 64);
        }
        if (m16 == 0) { rs[lr][wcol] = s; rq[lr][wcol] = qq; }
      }
    __syncthreads();
#pragma unroll
    for (int mf = 0; mf < 2; ++mf)
#pragma unroll
      for (int reg = 0; reg < 4; ++reg) {
        int lr = wrow * 32 + mf * 16 + quad * 4 + reg;
        int gr = blockIdx.y * 64 + lr;
        float mean = (rs[lr][0] + rs[lr][1]) * (1.f / 128.f);
        float var = (rq[lr][0] + rq[lr][1]) * (1.f / 128.f) - mean * mean;
        float rstd = rsqrtf(var + EPS_);
#pragma unroll
        for (int nf = 0; nf < 4; ++nf) {
          int c = wcol * 64 + nf * 16 + m16;
          C[(size_t)gr * 128 + c] = (acc[mf][nf][reg] - mean) * rstd * lng[c] + lnb[c];
        }
      }
  }
}

// ---------------- MFMA attention on packed QKV; O overwrites the V slice ----------------
__global__ __launch_bounds__(256) void attn_mfma(float* __restrict__ qkv) {
  const int h = blockIdx.x & (H_ - 1);
  const int bn = blockIdx.x >> 3;
  const int wave = threadIdx.x >> 6;
  const int lane = threadIdx.x & 63;
  const int m16 = lane & 15;
  const int quad = lane >> 4;
  const int row0 = wave * 32;
  const float* Qb = qkv + (size_t)bn * T_ * QLD + h * DH;
  const float* Kb = Qb + 128;
  const float* Vb = Qb + 256;
  float* Ob = (float*)Vb;

  __shared__ __bf16 Plds[4][32][136];

  bf16x8 qhi[2], qlo[2];
#pragma unroll
  for (int mf = 0; mf < 2; ++mf) {
    if (quad < 2) {
      const float* ap = Qb + (size_t)(row0 + mf * 16 + m16) * QLD + quad * 8;
      float4 x0 = *(const float4*)ap;
      float4 x1 = *(const float4*)(ap + 4);
      float xv[8] = {x0.x, x0.y, x0.z, x0.w, x1.x, x1.y, x1.z, x1.w};
#pragma unroll
      for (int j = 0; j < 8; ++j) {
        __bf16 hh = (__bf16)xv[j];
        qhi[mf][j] = hh;
        qlo[mf][j] = (__bf16)(xv[j] - (float)hh);
      }
    } else {
#pragma unroll
      for (int j = 0; j < 8; ++j) { qhi[mf][j] = (__bf16)0.f; qlo[mf][j] = (__bf16)0.f; }
    }
  }

  f32x4 acc[2][8] = {};
#pragma unroll
  for (int nf = 0; nf < 8; ++nf) {
    bf16x8 khi, klo;
    if (quad < 2) {
      const float* kp = Kb + (size_t)(nf * 16 + m16) * QLD + quad * 8;
      float4 x0 = *(const float4*)kp;
      float4 x1 = *(const float4*)(kp + 4);
      float xv[8] = {x0.x, x0.y, x0.z, x0.w, x1.x, x1.y, x1.z, x1.w};
#pragma unroll
      for (int j = 0; j < 8; ++j) {
        __bf16 hh = (__bf16)xv[j];
        khi[j] = hh;
        klo[j] = (__bf16)(xv[j] - (float)hh);
      }
    } else {
#pragma unroll
      for (int j = 0; j < 8; ++j) { khi[j] = (__bf16)0.f; klo[j] = (__bf16)0.f; }
    }
#pragma unroll
    for (int mf = 0; mf < 2; ++mf) {
      acc[mf][nf] = __builtin_amdgcn_mfma_f32_16x16x32_bf16(qhi[mf], khi, acc[mf][nf], 0, 0, 0);
      acc[mf][nf] = __builtin_amdgcn_mfma_f32_16x16x32_bf16(qhi[mf], klo, acc[mf][nf], 0, 0, 0);
      acc[mf][nf] = __builtin_amdgcn_mfma_f32_16x16x32_bf16(qlo[mf], khi, acc[mf][nf], 0, 0, 0);
    }
  }

  const float scale = 0.25f;
#pragma unroll
  for (int mf = 0; mf < 2; ++mf)
#pragma unroll
    for (int reg = 0; reg < 4; ++reg) {
      float mx = -1e30f;
#pragma unroll
      for (int nf = 0; nf < 8; ++nf) mx = fmaxf(mx, acc[mf][nf][reg]);
#pragma unroll
      for (int off = 1; off < 16; off <<= 1) mx = fmaxf(mx, __shfl_xor(mx, off, 64));
      float sum = 0.f;
#pragma unroll
      for (int nf = 0; nf < 8; ++nf) {
        float e = __expf((acc[mf][nf][reg] - mx) * scale);
        acc[mf][nf][reg] = e;
        sum += e;
      }
#pragma unroll
      for (int off = 1; off < 16; off <<= 1) sum += __shfl_xor(sum, off, 64);
      float inv = 1.f / sum;
#pragma unroll
      for (int nf = 0; nf < 8; ++nf) acc[mf][nf][reg] *= inv;
    }

#pragma unroll
  for (int mf = 0; mf < 2; ++mf)
#pragma unroll
    for (int nf = 0; nf < 8; ++nf)
#pragma unroll
      for (int reg = 0; reg < 4; ++reg)
        Plds[wave][mf * 16 + quad * 4 + reg][nf * 16 + m16] = (__bf16)acc[mf][nf][reg];

  f32x4 oacc[2] = {};
#pragma unroll
  for (int kc = 0; kc < 4; ++kc) {
    bf16x8 pa0 = *(const bf16x8*)&Plds[wave][m16][kc * 32 + quad * 8];
    bf16x8 pa1 = *(const bf16x8*)&Plds[wave][16 + m16][kc * 32 + quad * 8];
    bf16x8 vhi, vlo;
#pragma unroll
    for (int j = 0; j < 8; ++j) {
      float x = Vb[(size_t)(kc * 32 + quad * 8 + j) * QLD + m16];
      __bf16 hh = (__bf16)x;
      vhi[j] = hh;
      vlo[j] = (__bf16)(x - (float)hh);
    }
    oacc[0] = __builtin_amdgcn_mfma_f32_16x16x32_bf16(pa0, vhi, oacc[0], 0, 0, 0);
    oacc[0] = __builtin_amdgcn_mfma_f32_16x16x32_bf16(pa0, vlo, oacc[0], 0, 0, 0);
    oacc[1] = __builtin_amdgcn_mfma_f32_16x16x32_bf16(pa1, vhi, oacc[1], 0, 0, 0);
    oacc[1] = __builtin_amdgcn_mfma_f32_16x16x32_bf16(pa1, vlo, oacc[1], 0, 0, 0);
  }

  __syncthreads();
#pragma unroll
  for (int mf = 0; mf < 2; ++mf)
#pragma unroll
    for (int reg = 0; reg < 4; ++reg) {
      int r = row0 + mf * 16 + quad * 4 + reg;
      Ob[(size_t)r * QLD + m16] = oacc[mf][reg];
    }
}

// ---------------- gating dot ----------------
__global__ __launch_bounds__(256) void sdot_kernel(
    const float* __restrict__ e, const float* __restrict__ x, float* __restrict__ s) {
  int r = blockIdx.x * 4 + (threadIdx.x >> 6);
  int lane = threadIdx.x & 63;
  const float* ep = e + (size_t)r * D_;
  const float* xp = x + (size_t)r * D_;
  float acc = ep[lane] * xp[lane] + ep[lane + 64] * xp[lane + 64];
#pragma unroll
  for (int off = 32; off; off >>= 1) acc += __shfl_down(acc, off, 64);
  if (lane == 0) {
    int t = r & (T_ - 1);
    int bn = r >> 7;
    int n = bn & (NA - 1);
    int b = bn >> 6;
    s[(size_t)b * NN + t * NA + n] = acc;
  }
}

// ---------------- edge scatter ----------------
__global__ __launch_bounds__(256) void scatter_kernel(
    const float* __restrict__ s, const int* __restrict__ ei,
    const float* __restrict__ ew, float* __restrict__ g) {
  int idx = blockIdx.x * 256 + threadIdx.x;
  if (idx >= B_ * E_) return;
  int b = idx >> 16;
  int e = idx & (E_ - 1);
  int src = ei[(size_t)b * 2 * E_ + e];
  int dst = ei[(size_t)b * 2 * E_ + E_ + e];
  float w = ew[(size_t)b * E_ + e];
  atomicAdd(&g[(size_t)b * NN + dst], w * s[(size_t)b * NN + src]);
}

// ---------------- partial sums for global mean/var ----------------
__global__ __launch_bounds__(256) void stats_partial(
    const float* __restrict__ g, float* __restrict__ st) {
  int i = blockIdx.x * 256 + threadIdx.x;
  float v = g[i];
  float sum = v, sq = v * v;
#pragma unroll
  for (int off = 32; off; off >>= 1) {
    sum += __shfl_down(sum, off, 64);
    sq += __shfl_down(sq, off, 64);
  }
  __shared__ float s1[4], s2[4];
  int w = threadIdx.x >> 6;
  if ((threadIdx.x & 63) == 0) { s1[w] = sum; s2[w] = sq; }
  __syncthreads();
  if (threadIdx.x == 0) {
    atomicAdd(&st[0], s1[0] + s1[1] + s1[2] + s1[3]);
    atomicAdd(&st[1], s2[0] + s2[1] + s2[2] + s2[3]);
  }
}

// ---------------- final (fp32 out) ----------------
__global__ __launch_bounds__(256) void final_kernel(
    const float* __restrict__ g, const float* __restrict__ st,
    const float* __restrict__ bng, const float* __restrict__ bnb,
    const float* __restrict__ lw, const float* __restrict__ lb,
    float* __restrict__ out) {
  int idx = blockIdx.x * 256 + threadIdx.x;
  if (idx >= NTOT * D_) return;
  int d = idx & (D_ - 1);
  int r = idx >> 7;
  int t = r & (T_ - 1);
  int bn = r >> 7;
  int n = bn & (NA - 1);
  int b = bn >> 6;
  const float invn = 1.f / (float)(B_ * NN);
  float m = st[0] * invn;
  float var = st[1] * invn - m * m;
  float rs = rsqrtf(var + EPS_);
  float gv = g[(size_t)b * NN + t * NA + n];
  float val = (gv - m) * rs * bng[0] + bnb[0];
  out[idx] = val * lw[d] + lb[d];
}

extern "C" void kernel_launch(void* const* d_in, const int* in_sizes, int n_in,
                              void* d_out, int out_size, void* d_ws, size_t ws_size,
                              hipStream_t stream) {
  const float* hist = (const float*)d_in[0];
  const int* eidx = (const int*)d_in[1];
  const float* ew = (const float*)d_in[2];
  const float* hw = (const float*)d_in[3];
  const float* hb = (const float*)d_in[4];
  const float* wq = (const float*)d_in[5];
  const float* bq = (const float*)d_in[6];
  const float* wk = (const float*)d_in[7];
  const float* bk = (const float*)d_in[8];
  const float* wv = (const float*)d_in[9];
  const float* bv = (const float*)d_in[10];
  const float* wo = (const float*)d_in[11];
  const float* bo = (const float*)d_in[12];
  const float* ln1g = (const float*)d_in[13];
  const float* ln1b = (const float*)d_in[14];
  const float* w1 = (const float*)d_in[15];
  const float* b1 = (const float*)d_in[16];
  const float* w2 = (const float*)d_in[17];
  const float* b2 = (const float*)d_in[18];
  const float* ln2g = (const float*)d_in[19];
  const float* ln2b = (const float*)d_in[20];
  const float* bng = (const float*)d_in[21];
  const float* bnb = (const float*)d_in[22];
  const float* lgw = (const float*)d_in[23];
  const float* lgb = (const float*)d_in[24];
  float* out = (float*)d_out;

  float* ws = (float*)d_ws;
  const size_t NE = (size_t)NTOT * D_;
  float* bx = ws + 0 * NE;
  float* be = ws + 1 * NE;
  float* h1 = ws + 2 * NE;
  float* qkv = ws + 3 * NE;   // 3NE, [row][384]
  float* ffmid = ws + 3 * NE; // 4NE, overlaps dead qkv
  float* bs_ = ws + 7 * NE;
  float* bg_ = bs_ + NTOT;
  float* bst = bg_ + NTOT;
  float* pbias = bst + 2;
  const int LW = 196608;
  __bf16* whiB = (__bf16*)(pbias + L_ * QLD);
  __bf16* wloB = whiB + (size_t)L_ * LW;

  convert_weights<<<(L_ * LW + 255) / 256, 256, 0, stream>>>(
      wq, wk, wv, wo, w1, w2, whiB, wloB);
  bias_pack<<<(L_ * QLD + 255) / 256, 256, 0, stream>>>(bq, bk, bv, pbias);
  embed_kernel<<<(NTOT * D_) / 256, 256, 0, stream>>>(hist, hw, hb, bx, be);

  for (int l = 0; l < L_; ++l) {
    const __bf16* hiL = whiB + (size_t)l * LW;
    const __bf16* loL = wloB + (size_t)l * LW;
    // QKV: one N=384 GEMM into packed [row][384]
    gemm2<0><<<dim3(3, NTOT / 64), 256, 0, stream>>>(
        be, 128, hiL, loL, pbias + l * QLD, nullptr, nullptr, nullptr,
        qkv, QLD, 128);
    attn_mfma<<<B_ * NA * H_, 256, 0, stream>>>(qkv);
    // O-proj + residual(be) + LN1 -> h1
    gemm2<2><<<dim3(1, NTOT / 64), 256, 0, stream>>>(
        qkv + 256, QLD, hiL + 49152, loL + 49152, bo + l * D_, be,
        ln1g + l * D_, ln1b + l * D_, h1, 128, 128);
    // FF1 (relu) -> ffmid
    gemm2<1><<<dim3(4, NTOT / 64), 256, 0, stream>>>(
        h1, 128, hiL + 65536, loL + 65536, b1 + l * DFF, nullptr, nullptr, nullptr,
        ffmid, 512, 128);
    // FF2 + residual(h1) + LN2 -> be
    gemm2<2><<<dim3(1, NTOT / 64), 256, 0, stream>>>(
        ffmid, 512, hiL + 131072, loL + 131072, b2 + l * D_, h1,
        ln2g + l * D_, ln2b + l * D_, be, 128, DFF);
  }

  sdot_kernel<<<NTOT / 4, 256, 0, stream>>>(be, bx, bs_);
  hipMemsetAsync(bg_, 0, ((size_t)B_ * NN + 2) * sizeof(float), stream);
  scatter_kernel<<<(B_ * E_) / 256, 256, 0, stream>>>(bs_, eidx, ew, bg_);
  stats_partial<<<(B_ * NN) / 256, 256, 0, stream>>>(bg_, bst);
  final_kernel<<<(NTOT * D_) / 256, 256, 0, stream>>>(bg_, bst, bng, bnb, lgw, lgb, out);
}

// Round 10
// 682.294 us; speedup vs baseline: 1.1409x; 1.1129x over previous
//
#include <hip/hip_runtime.h>
#include <hip/hip_bf16.h>
#include <math.h>

#define EPS_ 1e-5f
constexpr int B_ = 4, NA = 64, T_ = 128, D_ = 128, H_ = 8, L_ = 3, DFF = 512, E_ = 65536;
constexpr int DH = D_ / H_;        // 16
constexpr int NN = T_ * NA;        // 8192
constexpr int NTOT = B_ * NA * T_; // 32768
constexpr int QLD = 384;           // packed QKV row stride

typedef __bf16 bf16x8 __attribute__((ext_vector_type(8)));
typedef float f32x4 __attribute__((ext_vector_type(4)));

// ---------------- embed: x = hist@W + b ; e = x + posenc ----------------
__global__ __launch_bounds__(256) void embed_kernel(
    const float* __restrict__ hist, const float* __restrict__ w,
    const float* __restrict__ b, float* __restrict__ x, float* __restrict__ e) {
  int idx = blockIdx.x * 256 + threadIdx.x;
  if (idx >= NTOT * D_) return;
  int d = idx & (D_ - 1);
  int r = idx >> 7;
  int t = r & (T_ - 1);
  const float* hp = hist + (size_t)r * 3;
  float acc = b[d];
  acc += hp[0] * w[0 * D_ + d];
  acc += hp[1] * w[1 * D_ + d];
  acc += hp[2] * w[2 * D_ + d];
  x[idx] = acc;
  int p = d >> 1;
  float ang = (float)t * expf(-logf(10000.f) * (2.f * (float)p) / (float)D_);
  float pe = (d & 1) ? cosf(ang) : sinf(ang);
  e[idx] = acc + pe;
}

// ---------------- weight split+transpose into [N][K] bf16 hi/lo, QKV packed ----------------
__global__ __launch_bounds__(256) void convert_weights(
    const float* __restrict__ wq, const float* __restrict__ wk,
    const float* __restrict__ wv, const float* __restrict__ wo,
    const float* __restrict__ w1, const float* __restrict__ w2,
    __bf16* __restrict__ hi, __bf16* __restrict__ lo) {
  const int LW = 196608;
  int idx = blockIdx.x * 256 + threadIdx.x;
  if (idx >= L_ * LW) return;
  int l = idx / LW;
  int rem = idx - l * LW;
  float src;
  int dst;
  if (rem < 49152) {
    int n = rem >> 7, k = rem & 127; // n in [0,384)
    int which = n >> 7, nl = n & 127;
    const float* W = (which == 0) ? wq : (which == 1) ? wk : wv;
    src = W[(size_t)l * 16384 + k * 128 + nl];
    dst = l * LW + n * 128 + k;
  } else if (rem < 65536) {
    int r2 = rem - 49152;
    int n = r2 >> 7, k = r2 & 127;
    src = wo[(size_t)l * 16384 + k * 128 + n];
    dst = l * LW + 49152 + n * 128 + k;
  } else if (rem < 131072) {
    int r2 = rem - 65536;
    int n = r2 >> 7, k = r2 & 127; // n in [0,512)
    src = w1[(size_t)l * 65536 + k * 512 + n];
    dst = l * LW + 65536 + n * 128 + k;
  } else {
    int r2 = rem - 131072;
    int n = r2 >> 9, k = r2 & 511; // n in [0,128), k in [0,512)
    src = w2[(size_t)l * 65536 + k * 128 + n];
    dst = l * LW + 131072 + n * 512 + k;
  }
  __bf16 h = (__bf16)src;
  hi[dst] = h;
  lo[dst] = (__bf16)(src - (float)h);
}

// ---------------- pack QKV biases: pb[l][384] = bq|bk|bv ----------------
__global__ __launch_bounds__(256) void bias_pack(
    const float* __restrict__ bq, const float* __restrict__ bk,
    const float* __restrict__ bv, float* __restrict__ pb) {
  int idx = blockIdx.x * 256 + threadIdx.x;
  if (idx >= L_ * QLD) return;
  int l = idx / QLD, n = idx - l * QLD;
  int which = n >> 7, nl = n & 127;
  const float* src = (which == 0) ? bq : (which == 1) ? bk : bv;
  pb[idx] = src[l * 128 + nl];
}

__device__ __forceinline__ void split8(const float* __restrict__ p,
                                       bf16x8& hi, bf16x8& lo) {
  float4 x0 = *(const float4*)p;
  float4 x1 = *(const float4*)(p + 4);
  float xv[8] = {x0.x, x0.y, x0.z, x0.w, x1.x, x1.y, x1.z, x1.w};
#pragma unroll
  for (int j = 0; j < 8; ++j) {
    __bf16 h = (__bf16)xv[j];
    hi[j] = h;
    lo[j] = (__bf16)(xv[j] - (float)h);
  }
}

// ---------------- MFMA GEMM, 128x128 tile (wave 64x64), compile-time K, unrolled ----------------
// EPI: 0=bias, 1=bias+relu. grid = (N/128, M/128).
template <int EPI, int K>
__global__ __launch_bounds__(256) void gemm_big(
    const float* __restrict__ A, int lda,
    const __bf16* __restrict__ Whi, const __bf16* __restrict__ Wlo,
    const float* __restrict__ bias,
    float* __restrict__ C, int ldc) {
  const int wave = threadIdx.x >> 6;
  const int lane = threadIdx.x & 63;
  const int m16 = lane & 15;
  const int quad = lane >> 4;
  const int wrow = wave >> 1, wcol = wave & 1;
  const int row0 = blockIdx.y * 128 + wrow * 64;
  const int col0 = blockIdx.x * 128 + wcol * 64;

  f32x4 acc[4][4] = {};
#pragma unroll
  for (int k0 = 0; k0 < K; k0 += 32) {
    bf16x8 ahi[4], alo[4];
#pragma unroll
    for (int mf = 0; mf < 4; ++mf)
      split8(A + (size_t)(row0 + mf * 16 + m16) * lda + k0 + quad * 8, ahi[mf], alo[mf]);
    bf16x8 bhi[4], blo[4];
#pragma unroll
    for (int nf = 0; nf < 4; ++nf) {
      size_t off = (size_t)(col0 + nf * 16 + m16) * K + k0 + quad * 8;
      bhi[nf] = *(const bf16x8*)(Whi + off);
      blo[nf] = *(const bf16x8*)(Wlo + off);
    }
#pragma unroll
    for (int mf = 0; mf < 4; ++mf)
#pragma unroll
      for (int nf = 0; nf < 4; ++nf) {
        acc[mf][nf] = __builtin_amdgcn_mfma_f32_16x16x32_bf16(ahi[mf], bhi[nf], acc[mf][nf], 0, 0, 0);
        acc[mf][nf] = __builtin_amdgcn_mfma_f32_16x16x32_bf16(ahi[mf], blo[nf], acc[mf][nf], 0, 0, 0);
        acc[mf][nf] = __builtin_amdgcn_mfma_f32_16x16x32_bf16(alo[mf], bhi[nf], acc[mf][nf], 0, 0, 0);
      }
  }
#pragma unroll
  for (int mf = 0; mf < 4; ++mf)
#pragma unroll
    for (int nf = 0; nf < 4; ++nf) {
      int c = col0 + nf * 16 + m16;
      float bj = bias[c];
#pragma unroll
      for (int reg = 0; reg < 4; ++reg) {
        int r = row0 + mf * 16 + quad * 4 + reg;
        float v = acc[mf][nf][reg] + bj;
        if (EPI == 1) v = fmaxf(v, 0.f);
        C[(size_t)r * ldc + c] = v;
      }
    }
}

// ---------------- GEMM + bias + resid + LayerNorm; block 64x128, compile-time K ----------------
template <int K>
__global__ __launch_bounds__(256) void gemm_ln(
    const float* __restrict__ A, int lda,
    const __bf16* __restrict__ Whi, const __bf16* __restrict__ Wlo,
    const float* __restrict__ bias, const float* __restrict__ resid,
    const float* __restrict__ lng, const float* __restrict__ lnb,
    float* __restrict__ C) {
  const int wave = threadIdx.x >> 6;
  const int lane = threadIdx.x & 63;
  const int m16 = lane & 15;
  const int quad = lane >> 4;
  const int wrow = wave >> 1, wcol = wave & 1;
  const int row0 = blockIdx.y * 64 + wrow * 32;
  const int col0 = wcol * 64;

  f32x4 acc[2][4] = {};
#pragma unroll 4
  for (int k0 = 0; k0 < K; k0 += 32) {
    bf16x8 ahi[2], alo[2];
#pragma unroll
    for (int mf = 0; mf < 2; ++mf)
      split8(A + (size_t)(row0 + mf * 16 + m16) * lda + k0 + quad * 8, ahi[mf], alo[mf]);
    bf16x8 bhi[4], blo[4];
#pragma unroll
    for (int nf = 0; nf < 4; ++nf) {
      size_t off = (size_t)(col0 + nf * 16 + m16) * K + k0 + quad * 8;
      bhi[nf] = *(const bf16x8*)(Whi + off);
      blo[nf] = *(const bf16x8*)(Wlo + off);
    }
#pragma unroll
    for (int mf = 0; mf < 2; ++mf)
#pragma unroll
      for (int nf = 0; nf < 4; ++nf) {
        acc[mf][nf] = __builtin_amdgcn_mfma_f32_16x16x32_bf16(ahi[mf], bhi[nf], acc[mf][nf], 0, 0, 0);
        acc[mf][nf] = __builtin_amdgcn_mfma_f32_16x16x32_bf16(ahi[mf], blo[nf], acc[mf][nf], 0, 0, 0);
        acc[mf][nf] = __builtin_amdgcn_mfma_f32_16x16x32_bf16(alo[mf], bhi[nf], acc[mf][nf], 0, 0, 0);
      }
  }
  __shared__ float rs[64][2], rq[64][2];
#pragma unroll
  for (int mf = 0; mf < 2; ++mf)
#pragma unroll
    for (int reg = 0; reg < 4; ++reg) {
      int lr = wrow * 32 + mf * 16 + quad * 4 + reg;
      int gr = blockIdx.y * 64 + lr;
      float s = 0.f, qq = 0.f;
#pragma unroll
      for (int nf = 0; nf < 4; ++nf) {
        int c = col0 + nf * 16 + m16;
        float v = acc[mf][nf][reg] + bias[c] + resid[(size_t)gr * 128 + c];
        acc[mf][nf][reg] = v;
        s += v;
        qq += v * v;
      }
#pragma unroll
      for (int off = 1; off < 16; off <<= 1) {
        s += __shfl_xor(s, off, 64);
        qq += __shfl_xor(qq, off, 64);
      }
      if (m16 == 0) { rs[lr][wcol] = s; rq[lr][wcol] = qq; }
    }
  __syncthreads();
#pragma unroll
  for (int mf = 0; mf < 2; ++mf)
#pragma unroll
    for (int reg = 0; reg < 4; ++reg) {
      int lr = wrow * 32 + mf * 16 + quad * 4 + reg;
      int gr = blockIdx.y * 64 + lr;
      float mean = (rs[lr][0] + rs[lr][1]) * (1.f / 128.f);
      float var = (rq[lr][0] + rq[lr][1]) * (1.f / 128.f) - mean * mean;
      float rstd = rsqrtf(var + EPS_);
#pragma unroll
      for (int nf = 0; nf < 4; ++nf) {
        int c = col0 + nf * 16 + m16;
        C[(size_t)gr * 128 + c] = (acc[mf][nf][reg] - mean) * rstd * lng[c] + lnb[c];
      }
    }
}

// ---------------- MFMA attention on packed QKV; O overwrites the V slice ----------------
__global__ __launch_bounds__(256) void attn_mfma(float* __restrict__ qkv) {
  const int h = blockIdx.x & (H_ - 1);
  const int bn = blockIdx.x >> 3;
  const int wave = threadIdx.x >> 6;
  const int lane = threadIdx.x & 63;
  const int m16 = lane & 15;
  const int quad = lane >> 4;
  const int row0 = wave * 32;
  const float* Qb = qkv + (size_t)bn * T_ * QLD + h * DH;
  const float* Kb = Qb + 128;
  const float* Vb = Qb + 256;
  float* Ob = (float*)Vb;

  __shared__ __bf16 Plds[4][32][136];

  bf16x8 qhi[2], qlo[2];
#pragma unroll
  for (int mf = 0; mf < 2; ++mf) {
    if (quad < 2) {
      split8(Qb + (size_t)(row0 + mf * 16 + m16) * QLD + quad * 8, qhi[mf], qlo[mf]);
    } else {
#pragma unroll
      for (int j = 0; j < 8; ++j) { qhi[mf][j] = (__bf16)0.f; qlo[mf][j] = (__bf16)0.f; }
    }
  }

  f32x4 acc[2][8] = {};
#pragma unroll
  for (int nf = 0; nf < 8; ++nf) {
    bf16x8 khi, klo;
    if (quad < 2) {
      split8(Kb + (size_t)(nf * 16 + m16) * QLD + quad * 8, khi, klo);
    } else {
#pragma unroll
      for (int j = 0; j < 8; ++j) { khi[j] = (__bf16)0.f; klo[j] = (__bf16)0.f; }
    }
#pragma unroll
    for (int mf = 0; mf < 2; ++mf) {
      acc[mf][nf] = __builtin_amdgcn_mfma_f32_16x16x32_bf16(qhi[mf], khi, acc[mf][nf], 0, 0, 0);
      acc[mf][nf] = __builtin_amdgcn_mfma_f32_16x16x32_bf16(qhi[mf], klo, acc[mf][nf], 0, 0, 0);
      acc[mf][nf] = __builtin_amdgcn_mfma_f32_16x16x32_bf16(qlo[mf], khi, acc[mf][nf], 0, 0, 0);
    }
  }

  const float scale = 0.25f;
#pragma unroll
  for (int mf = 0; mf < 2; ++mf)
#pragma unroll
    for (int reg = 0; reg < 4; ++reg) {
      float mx = -1e30f;
#pragma unroll
      for (int nf = 0; nf < 8; ++nf) mx = fmaxf(mx, acc[mf][nf][reg]);
#pragma unroll
      for (int off = 1; off < 16; off <<= 1) mx = fmaxf(mx, __shfl_xor(mx, off, 64));
      float sum = 0.f;
#pragma unroll
      for (int nf = 0; nf < 8; ++nf) {
        float e = __expf((acc[mf][nf][reg] - mx) * scale);
        acc[mf][nf][reg] = e;
        sum += e;
      }
#pragma unroll
      for (int off = 1; off < 16; off <<= 1) sum += __shfl_xor(sum, off, 64);
      float inv = 1.f / sum;
#pragma unroll
      for (int nf = 0; nf < 8; ++nf) acc[mf][nf][reg] *= inv;
    }

#pragma unroll
  for (int mf = 0; mf < 2; ++mf)
#pragma unroll
    for (int nf = 0; nf < 8; ++nf)
#pragma unroll
      for (int reg = 0; reg < 4; ++reg)
        Plds[wave][mf * 16 + quad * 4 + reg][nf * 16 + m16] = (__bf16)acc[mf][nf][reg];

  f32x4 oacc[2] = {};
#pragma unroll
  for (int kc = 0; kc < 4; ++kc) {
    bf16x8 pa0 = *(const bf16x8*)&Plds[wave][m16][kc * 32 + quad * 8];
    bf16x8 pa1 = *(const bf16x8*)&Plds[wave][16 + m16][kc * 32 + quad * 8];
    bf16x8 vhi, vlo;
#pragma unroll
    for (int j = 0; j < 8; ++j) {
      float x = Vb[(size_t)(kc * 32 + quad * 8 + j) * QLD + m16];
      __bf16 hh = (__bf16)x;
      vhi[j] = hh;
      vlo[j] = (__bf16)(x - (float)hh);
    }
    oacc[0] = __builtin_amdgcn_mfma_f32_16x16x32_bf16(pa0, vhi, oacc[0], 0, 0, 0);
    oacc[0] = __builtin_amdgcn_mfma_f32_16x16x32_bf16(pa0, vlo, oacc[0], 0, 0, 0);
    oacc[1] = __builtin_amdgcn_mfma_f32_16x16x32_bf16(pa1, vhi, oacc[1], 0, 0, 0);
    oacc[1] = __builtin_amdgcn_mfma_f32_16x16x32_bf16(pa1, vlo, oacc[1], 0, 0, 0);
  }

  __syncthreads();
#pragma unroll
  for (int mf = 0; mf < 2; ++mf)
#pragma unroll
    for (int reg = 0; reg < 4; ++reg) {
      int r = row0 + mf * 16 + quad * 4 + reg;
      Ob[(size_t)r * QLD + m16] = oacc[mf][reg];
    }
}

// ---------------- gating dot ----------------
__global__ __launch_bounds__(256) void sdot_kernel(
    const float* __restrict__ e, const float* __restrict__ x, float* __restrict__ s) {
  int r = blockIdx.x * 4 + (threadIdx.x >> 6);
  int lane = threadIdx.x & 63;
  const float* ep = e + (size_t)r * D_;
  const float* xp = x + (size_t)r * D_;
  float acc = ep[lane] * xp[lane] + ep[lane + 64] * xp[lane + 64];
#pragma unroll
  for (int off = 32; off; off >>= 1) acc += __shfl_down(acc, off, 64);
  if (lane == 0) {
    int t = r & (T_ - 1);
    int bn = r >> 7;
    int n = bn & (NA - 1);
    int b = bn >> 6;
    s[(size_t)b * NN + t * NA + n] = acc;
  }
}

// ---------------- edge scatter ----------------
__global__ __launch_bounds__(256) void scatter_kernel(
    const float* __restrict__ s, const int* __restrict__ ei,
    const float* __restrict__ ew, float* __restrict__ g) {
  int idx = blockIdx.x * 256 + threadIdx.x;
  if (idx >= B_ * E_) return;
  int b = idx >> 16;
  int e = idx & (E_ - 1);
  int src = ei[(size_t)b * 2 * E_ + e];
  int dst = ei[(size_t)b * 2 * E_ + E_ + e];
  float w = ew[(size_t)b * E_ + e];
  atomicAdd(&g[(size_t)b * NN + dst], w * s[(size_t)b * NN + src]);
}

// ---------------- partial sums for global mean/var ----------------
__global__ __launch_bounds__(256) void stats_partial(
    const float* __restrict__ g, float* __restrict__ st) {
  int i = blockIdx.x * 256 + threadIdx.x;
  float v = g[i];
  float sum = v, sq = v * v;
#pragma unroll
  for (int off = 32; off; off >>= 1) {
    sum += __shfl_down(sum, off, 64);
    sq += __shfl_down(sq, off, 64);
  }
  __shared__ float s1[4], s2[4];
  int w = threadIdx.x >> 6;
  if ((threadIdx.x & 63) == 0) { s1[w] = sum; s2[w] = sq; }
  __syncthreads();
  if (threadIdx.x == 0) {
    atomicAdd(&st[0], s1[0] + s1[1] + s1[2] + s1[3]);
    atomicAdd(&st[1], s2[0] + s2[1] + s2[2] + s2[3]);
  }
}

// ---------------- final (fp32 out) ----------------
__global__ __launch_bounds__(256) void final_kernel(
    const float* __restrict__ g, const float* __restrict__ st,
    const float* __restrict__ bng, const float* __restrict__ bnb,
    const float* __restrict__ lw, const float* __restrict__ lb,
    float* __restrict__ out) {
  int idx = blockIdx.x * 256 + threadIdx.x;
  if (idx >= NTOT * D_) return;
  int d = idx & (D_ - 1);
  int r = idx >> 7;
  int t = r & (T_ - 1);
  int bn = r >> 7;
  int n = bn & (NA - 1);
  int b = bn >> 6;
  const float invn = 1.f / (float)(B_ * NN);
  float m = st[0] * invn;
  float var = st[1] * invn - m * m;
  float rs = rsqrtf(var + EPS_);
  float gv = g[(size_t)b * NN + t * NA + n];
  float val = (gv - m) * rs * bng[0] + bnb[0];
  out[idx] = val * lw[d] + lb[d];
}

extern "C" void kernel_launch(void* const* d_in, const int* in_sizes, int n_in,
                              void* d_out, int out_size, void* d_ws, size_t ws_size,
                              hipStream_t stream) {
  const float* hist = (const float*)d_in[0];
  const int* eidx = (const int*)d_in[1];
  const float* ew = (const float*)d_in[2];
  const float* hw = (const float*)d_in[3];
  const float* hb = (const float*)d_in[4];
  const float* wq = (const float*)d_in[5];
  const float* bq = (const float*)d_in[6];
  const float* wk = (const float*)d_in[7];
  const float* bk = (const float*)d_in[8];
  const float* wv = (const float*)d_in[9];
  const float* bv = (const float*)d_in[10];
  const float* wo = (const float*)d_in[11];
  const float* bo = (const float*)d_in[12];
  const float* ln1g = (const float*)d_in[13];
  const float* ln1b = (const float*)d_in[14];
  const float* w1 = (const float*)d_in[15];
  const float* b1 = (const float*)d_in[16];
  const float* w2 = (const float*)d_in[17];
  const float* b2 = (const float*)d_in[18];
  const float* ln2g = (const float*)d_in[19];
  const float* ln2b = (const float*)d_in[20];
  const float* bng = (const float*)d_in[21];
  const float* bnb = (const float*)d_in[22];
  const float* lgw = (const float*)d_in[23];
  const float* lgb = (const float*)d_in[24];
  float* out = (float*)d_out;

  float* ws = (float*)d_ws;
  const size_t NE = (size_t)NTOT * D_;
  float* bx = ws + 0 * NE;
  float* be = ws + 1 * NE;
  float* h1 = ws + 2 * NE;
  float* qkv = ws + 3 * NE;   // 3NE, [row][384]
  float* ffmid = ws + 3 * NE; // 4NE, overlaps dead qkv
  float* bs_ = ws + 7 * NE;
  float* bg_ = bs_ + NTOT;
  float* bst = bg_ + NTOT;
  float* pbias = bst + 2;
  const int LW = 196608;
  __bf16* whiB = (__bf16*)(pbias + L_ * QLD);
  __bf16* wloB = whiB + (size_t)L_ * LW;

  convert_weights<<<(L_ * LW + 255) / 256, 256, 0, stream>>>(
      wq, wk, wv, wo, w1, w2, whiB, wloB);
  bias_pack<<<(L_ * QLD + 255) / 256, 256, 0, stream>>>(bq, bk, bv, pbias);
  embed_kernel<<<(NTOT * D_) / 256, 256, 0, stream>>>(hist, hw, hb, bx, be);

  for (int l = 0; l < L_; ++l) {
    const __bf16* hiL = whiB + (size_t)l * LW;
    const __bf16* loL = wloB + (size_t)l * LW;
    // QKV: one N=384 GEMM into packed [row][384]
    gemm_big<0, 128><<<dim3(3, NTOT / 128), 256, 0, stream>>>(
        be, 128, hiL, loL, pbias + l * QLD, qkv, QLD);
    attn_mfma<<<B_ * NA * H_, 256, 0, stream>>>(qkv);
    // O-proj + residual(be) + LN1 -> h1
    gemm_ln<128><<<dim3(1, NTOT / 64), 256, 0, stream>>>(
        qkv + 256, QLD, hiL + 49152, loL + 49152, bo + l * D_, be,
        ln1g + l * D_, ln1b + l * D_, h1);
    // FF1 (relu) -> ffmid
    gemm_big<1, 128><<<dim3(4, NTOT / 128), 256, 0, stream>>>(
        h1, 128, hiL + 65536, loL + 65536, b1 + l * DFF, ffmid, 512);
    // FF2 + residual(h1) + LN2 -> be
    gemm_ln<512><<<dim3(1, NTOT / 64), 256, 0, stream>>>(
        ffmid, 512, hiL + 131072, loL + 131072, b2 + l * D_, h1,
        ln2g + l * D_, ln2b + l * D_, be);
  }

  sdot_kernel<<<NTOT / 4, 256, 0, stream>>>(be, bx, bs_);
  hipMemsetAsync(bg_, 0, ((size_t)B_ * NN + 2) * sizeof(float), stream);
  scatter_kernel<<<(B_ * E_) / 256, 256, 0, stream>>>(bs_, eidx, ew, bg_);
  stats_partial<<<(B_ * NN) / 256, 256, 0, stream>>>(bg_, bst);
  final_kernel<<<(NTOT * D_) / 256, 256, 0, stream>>>(bg_, bst, bng, bnb, lgw, lgb, out);
}

// Round 11
// 606.206 us; speedup vs baseline: 1.2841x; 1.1255x over previous
//
#include <hip/hip_runtime.h>
#include <hip/hip_bf16.h>
#include <math.h>

#define EPS_ 1e-5f
constexpr int B_ = 4, NA = 64, T_ = 128, D_ = 128, H_ = 8, L_ = 3, DFF = 512, E_ = 65536;
constexpr int DH = D_ / H_;        // 16
constexpr int NN = T_ * NA;        // 8192
constexpr int NTOT = B_ * NA * T_; // 32768
constexpr int QLD = 384;           // packed QKV row stride
constexpr size_t NE_ = (size_t)NTOT * D_;

typedef __bf16 bf16x8 __attribute__((ext_vector_type(8)));
typedef float f32x4 __attribute__((ext_vector_type(4)));

// ---------------- embed: x = hist@W + b ; e = x + posenc ----------------
__global__ __launch_bounds__(256) void embed_kernel(
    const float* __restrict__ hist, const float* __restrict__ w,
    const float* __restrict__ b, float* __restrict__ x, float* __restrict__ e) {
  int idx = blockIdx.x * 256 + threadIdx.x;
  if (idx >= NTOT * D_) return;
  int d = idx & (D_ - 1);
  int r = idx >> 7;
  int t = r & (T_ - 1);
  const float* hp = hist + (size_t)r * 3;
  float acc = b[d];
  acc += hp[0] * w[0 * D_ + d];
  acc += hp[1] * w[1 * D_ + d];
  acc += hp[2] * w[2 * D_ + d];
  x[idx] = acc;
  int p = d >> 1;
  float ang = (float)t * expf(-logf(10000.f) * (2.f * (float)p) / (float)D_);
  float pe = (d & 1) ? cosf(ang) : sinf(ang);
  e[idx] = acc + pe;
}

// ---------------- weight split into FRAGMENT-LINEAR bf16 hi/lo ----------------
// Per segment (N,K): element (n,k) -> tile nt=n>>4, kt=k>>5, lane=(k>>3&3)*16+(n&15),
// j=k&7; dst = ((nt*(K/32)+kt)*64+lane)*8+j. A wave's B-frag load is then
// base+lane*16B: one coalesced 1KB burst. Segments per layer (elem offsets):
// qkv(N=384,K=128)@0, wo(128,128)@49152, w1(512,128)@65536, w2(128,512)@131072.
__global__ __launch_bounds__(256) void convert_weights(
    const float* __restrict__ wq, const float* __restrict__ wk,
    const float* __restrict__ wv, const float* __restrict__ wo,
    const float* __restrict__ w1, const float* __restrict__ w2,
    __bf16* __restrict__ hi, __bf16* __restrict__ lo) {
  const int LW = 196608;
  int idx = blockIdx.x * 256 + threadIdx.x;
  if (idx >= L_ * LW) return;
  int l = idx / LW;
  int rem = idx - l * LW;
  float src;
  int n, k, K, segoff;
  if (rem < 49152) { // qkv: n in [0,384), k in [0,128)
    n = rem >> 7; k = rem & 127; K = 128; segoff = 0;
    int which = n >> 7, nl = n & 127;
    const float* W = (which == 0) ? wq : (which == 1) ? wk : wv;
    src = W[(size_t)l * 16384 + k * 128 + nl];
  } else if (rem < 65536) { // wo
    int r2 = rem - 49152;
    n = r2 >> 7; k = r2 & 127; K = 128; segoff = 49152;
    src = wo[(size_t)l * 16384 + k * 128 + n];
  } else if (rem < 131072) { // w1: n in [0,512), k in [0,128)
    int r2 = rem - 65536;
    n = r2 >> 7; k = r2 & 127; K = 128; segoff = 65536;
    src = w1[(size_t)l * 65536 + k * 512 + n];
  } else { // w2: n in [0,128), k in [0,512)
    int r2 = rem - 131072;
    n = r2 >> 9; k = r2 & 511; K = 512; segoff = 131072;
    src = w2[(size_t)l * 65536 + k * 128 + n];
  }
  int nt = n >> 4, kt = k >> 5;
  int lane = ((k >> 3) & 3) * 16 + (n & 15);
  int j = k & 7;
  int dst = l * LW + segoff + ((nt * (K / 32) + kt) * 64 + lane) * 8 + j;
  __bf16 h = (__bf16)src;
  hi[dst] = h;
  lo[dst] = (__bf16)(src - (float)h);
}

// ---------------- pack QKV biases: pb[l][384] = bq|bk|bv ----------------
__global__ __launch_bounds__(256) void bias_pack(
    const float* __restrict__ bq, const float* __restrict__ bk,
    const float* __restrict__ bv, float* __restrict__ pb) {
  int idx = blockIdx.x * 256 + threadIdx.x;
  if (idx >= L_ * QLD) return;
  int l = idx / QLD, n = idx - l * QLD;
  int which = n >> 7, nl = n & 127;
  const float* src = (which == 0) ? bq : (which == 1) ? bk : bv;
  pb[idx] = src[l * 128 + nl];
}

__device__ __forceinline__ void split8(const float* __restrict__ p,
                                       bf16x8& hi, bf16x8& lo) {
  float4 x0 = *(const float4*)p;
  float4 x1 = *(const float4*)(p + 4);
  float xv[8] = {x0.x, x0.y, x0.z, x0.w, x1.x, x1.y, x1.z, x1.w};
#pragma unroll
  for (int j = 0; j < 8; ++j) {
    __bf16 h = (__bf16)xv[j];
    hi[j] = h;
    lo[j] = (__bf16)(xv[j] - (float)h);
  }
}

// ---------------- MFMA GEMM, 128x128 tile (wave 64x64), frag-linear W ----------------
template <int EPI, int K>
__global__ __launch_bounds__(256) void gemm_big(
    const float* __restrict__ A, int lda,
    const __bf16* __restrict__ Whi, const __bf16* __restrict__ Wlo,
    const float* __restrict__ bias,
    float* __restrict__ C, int ldc) {
  const int wave = threadIdx.x >> 6;
  const int lane = threadIdx.x & 63;
  const int m16 = lane & 15;
  const int quad = lane >> 4;
  const int wrow = wave >> 1, wcol = wave & 1;
  const int row0 = blockIdx.y * 128 + wrow * 64;
  const int col0 = blockIdx.x * 128 + wcol * 64;
  const int ctb = col0 >> 4; // n-tile base

  f32x4 acc[4][4] = {};
#pragma unroll
  for (int k0 = 0; k0 < K; k0 += 32) {
    bf16x8 ahi[4], alo[4];
#pragma unroll
    for (int mf = 0; mf < 4; ++mf)
      split8(A + (size_t)(row0 + mf * 16 + m16) * lda + k0 + quad * 8, ahi[mf], alo[mf]);
    bf16x8 bhi[4], blo[4];
#pragma unroll
    for (int nf = 0; nf < 4; ++nf) {
      size_t off = ((size_t)(ctb + nf) * (K / 32) + (k0 >> 5)) * 512 + lane * 8;
      bhi[nf] = *(const bf16x8*)(Whi + off);
      blo[nf] = *(const bf16x8*)(Wlo + off);
    }
#pragma unroll
    for (int mf = 0; mf < 4; ++mf)
#pragma unroll
      for (int nf = 0; nf < 4; ++nf) {
        acc[mf][nf] = __builtin_amdgcn_mfma_f32_16x16x32_bf16(ahi[mf], bhi[nf], acc[mf][nf], 0, 0, 0);
        acc[mf][nf] = __builtin_amdgcn_mfma_f32_16x16x32_bf16(ahi[mf], blo[nf], acc[mf][nf], 0, 0, 0);
        acc[mf][nf] = __builtin_amdgcn_mfma_f32_16x16x32_bf16(alo[mf], bhi[nf], acc[mf][nf], 0, 0, 0);
      }
  }
#pragma unroll
  for (int mf = 0; mf < 4; ++mf)
#pragma unroll
    for (int nf = 0; nf < 4; ++nf) {
      int c = col0 + nf * 16 + m16;
      float bj = bias[c];
#pragma unroll
      for (int reg = 0; reg < 4; ++reg) {
        int r = row0 + mf * 16 + quad * 4 + reg;
        float v = acc[mf][nf][reg] + bj;
        if (EPI == 1) v = fmaxf(v, 0.f);
        C[(size_t)r * ldc + c] = v;
      }
    }
}

// ---------------- GEMM + bias + resid + LayerNorm; block 64x128, frag-linear W ----------------
template <int K>
__global__ __launch_bounds__(256) void gemm_ln(
    const float* __restrict__ A, int lda,
    const __bf16* __restrict__ Whi, const __bf16* __restrict__ Wlo,
    const float* __restrict__ bias, const float* __restrict__ resid,
    const float* __restrict__ lng, const float* __restrict__ lnb,
    float* __restrict__ C) {
  const int wave = threadIdx.x >> 6;
  const int lane = threadIdx.x & 63;
  const int m16 = lane & 15;
  const int quad = lane >> 4;
  const int wrow = wave >> 1, wcol = wave & 1;
  const int row0 = blockIdx.y * 64 + wrow * 32;
  const int col0 = wcol * 64;
  const int ctb = wcol * 4;

  f32x4 acc[2][4] = {};
#pragma unroll
  for (int k0 = 0; k0 < K; k0 += 32) {
    bf16x8 ahi[2], alo[2];
#pragma unroll
    for (int mf = 0; mf < 2; ++mf)
      split8(A + (size_t)(row0 + mf * 16 + m16) * lda + k0 + quad * 8, ahi[mf], alo[mf]);
    bf16x8 bhi[4], blo[4];
#pragma unroll
    for (int nf = 0; nf < 4; ++nf) {
      size_t off = ((size_t)(ctb + nf) * (K / 32) + (k0 >> 5)) * 512 + lane * 8;
      bhi[nf] = *(const bf16x8*)(Whi + off);
      blo[nf] = *(const bf16x8*)(Wlo + off);
    }
#pragma unroll
    for (int mf = 0; mf < 2; ++mf)
#pragma unroll
      for (int nf = 0; nf < 4; ++nf) {
        acc[mf][nf] = __builtin_amdgcn_mfma_f32_16x16x32_bf16(ahi[mf], bhi[nf], acc[mf][nf], 0, 0, 0);
        acc[mf][nf] = __builtin_amdgcn_mfma_f32_16x16x32_bf16(ahi[mf], blo[nf], acc[mf][nf], 0, 0, 0);
        acc[mf][nf] = __builtin_amdgcn_mfma_f32_16x16x32_bf16(alo[mf], bhi[nf], acc[mf][nf], 0, 0, 0);
      }
  }
  __shared__ float rs[64][2], rq[64][2];
#pragma unroll
  for (int mf = 0; mf < 2; ++mf)
#pragma unroll
    for (int reg = 0; reg < 4; ++reg) {
      int lr = wrow * 32 + mf * 16 + quad * 4 + reg;
      int gr = blockIdx.y * 64 + lr;
      float s = 0.f, qq = 0.f;
#pragma unroll
      for (int nf = 0; nf < 4; ++nf) {
        int c = col0 + nf * 16 + m16;
        float v = acc[mf][nf][reg] + bias[c] + resid[(size_t)gr * 128 + c];
        acc[mf][nf][reg] = v;
        s += v;
        qq += v * v;
      }
#pragma unroll
      for (int off = 1; off < 16; off <<= 1) {
        s += __shfl_xor(s, off, 64);
        qq += __shfl_xor(qq, off, 64);
      }
      if (m16 == 0) { rs[lr][wcol] = s; rq[lr][wcol] = qq; }
    }
  __syncthreads();
#pragma unroll
  for (int mf = 0; mf < 2; ++mf)
#pragma unroll
    for (int reg = 0; reg < 4; ++reg) {
      int lr = wrow * 32 + mf * 16 + quad * 4 + reg;
      int gr = blockIdx.y * 64 + lr;
      float mean = (rs[lr][0] + rs[lr][1]) * (1.f / 128.f);
      float var = (rq[lr][0] + rq[lr][1]) * (1.f / 128.f) - mean * mean;
      float rstd = rsqrtf(var + EPS_);
#pragma unroll
      for (int nf = 0; nf < 4; ++nf) {
        int c = col0 + nf * 16 + m16;
        C[(size_t)gr * 128 + c] = (acc[mf][nf][reg] - mean) * rstd * lng[c] + lnb[c];
      }
    }
}

// ---------------- FF2 split-K partial GEMM: K=512 in 4 chunks of 128 ----------------
// grid (4, M/64); block 64 rows x 128 cols; writes fp32 partial P[kc][M][128].
__global__ __launch_bounds__(256) void gemm_pk(
    const float* __restrict__ A, const __bf16* __restrict__ Whi,
    const __bf16* __restrict__ Wlo, float* __restrict__ P) {
  const int kc = blockIdx.x;
  const int wave = threadIdx.x >> 6;
  const int lane = threadIdx.x & 63;
  const int m16 = lane & 15;
  const int quad = lane >> 4;
  const int wrow = wave >> 1, wcol = wave & 1;
  const int row0 = blockIdx.y * 64 + wrow * 32;
  const int col0 = wcol * 64;
  const int ctb = wcol * 4;

  f32x4 acc[2][4] = {};
#pragma unroll
  for (int kt = 0; kt < 4; ++kt) {
    const int k0 = kc * 128 + kt * 32;
    bf16x8 ahi[2], alo[2];
#pragma unroll
    for (int mf = 0; mf < 2; ++mf)
      split8(A + (size_t)(row0 + mf * 16 + m16) * 512 + k0 + quad * 8, ahi[mf], alo[mf]);
    bf16x8 bhi[4], blo[4];
#pragma unroll
    for (int nf = 0; nf < 4; ++nf) {
      size_t off = ((size_t)(ctb + nf) * 16 + (k0 >> 5)) * 512 + lane * 8; // K/32=16
      bhi[nf] = *(const bf16x8*)(Whi + off);
      blo[nf] = *(const bf16x8*)(Wlo + off);
    }
#pragma unroll
    for (int mf = 0; mf < 2; ++mf)
#pragma unroll
      for (int nf = 0; nf < 4; ++nf) {
        acc[mf][nf] = __builtin_amdgcn_mfma_f32_16x16x32_bf16(ahi[mf], bhi[nf], acc[mf][nf], 0, 0, 0);
        acc[mf][nf] = __builtin_amdgcn_mfma_f32_16x16x32_bf16(ahi[mf], blo[nf], acc[mf][nf], 0, 0, 0);
        acc[mf][nf] = __builtin_amdgcn_mfma_f32_16x16x32_bf16(alo[mf], bhi[nf], acc[mf][nf], 0, 0, 0);
      }
  }
  float* out = P + (size_t)kc * NE_;
#pragma unroll
  for (int mf = 0; mf < 2; ++mf)
#pragma unroll
    for (int nf = 0; nf < 4; ++nf) {
      int c = col0 + nf * 16 + m16;
#pragma unroll
      for (int reg = 0; reg < 4; ++reg) {
        int r = row0 + mf * 16 + quad * 4 + reg;
        out[(size_t)r * 128 + c] = acc[mf][nf][reg];
      }
    }
}

// ---------------- reduce 4 partials + bias + resid -> LayerNorm ----------------
__global__ __launch_bounds__(128) void reduce_ln4(
    const float* __restrict__ P, const float* __restrict__ bias,
    const float* __restrict__ resid,
    const float* __restrict__ gam, const float* __restrict__ bet,
    float* __restrict__ out) {
  int r = blockIdx.x;
  int d = threadIdx.x;
  size_t o = (size_t)r * D_ + d;
  float val = P[o] + P[o + NE_] + P[o + 2 * NE_] + P[o + 3 * NE_] + bias[d] + resid[o];
  __shared__ float red[4];
  float s = val;
#pragma unroll
  for (int off = 32; off; off >>= 1) s += __shfl_down(s, off, 64);
  if ((d & 63) == 0) red[d >> 6] = s;
  __syncthreads();
  float mean = (red[0] + red[1]) * (1.f / (float)D_);
  float dv = val - mean;
  float q = dv * dv;
#pragma unroll
  for (int off = 32; off; off >>= 1) q += __shfl_down(q, off, 64);
  if ((d & 63) == 0) red[2 + (d >> 6)] = q;
  __syncthreads();
  float var = (red[2] + red[3]) * (1.f / (float)D_);
  out[o] = dv * rsqrtf(var + EPS_) * gam[d] + bet[d];
}

// ---------------- MFMA attention on packed QKV; O overwrites the V slice ----------------
__global__ __launch_bounds__(256) void attn_mfma(float* __restrict__ qkv) {
  const int h = blockIdx.x & (H_ - 1);
  const int bn = blockIdx.x >> 3;
  const int wave = threadIdx.x >> 6;
  const int lane = threadIdx.x & 63;
  const int m16 = lane & 15;
  const int quad = lane >> 4;
  const int row0 = wave * 32;
  const float* Qb = qkv + (size_t)bn * T_ * QLD + h * DH;
  const float* Kb = Qb + 128;
  const float* Vb = Qb + 256;
  float* Ob = (float*)Vb;

  __shared__ __bf16 Plds[4][32][136];

  bf16x8 qhi[2], qlo[2];
#pragma unroll
  for (int mf = 0; mf < 2; ++mf) {
    if (quad < 2) {
      split8(Qb + (size_t)(row0 + mf * 16 + m16) * QLD + quad * 8, qhi[mf], qlo[mf]);
    } else {
#pragma unroll
      for (int j = 0; j < 8; ++j) { qhi[mf][j] = (__bf16)0.f; qlo[mf][j] = (__bf16)0.f; }
    }
  }

  f32x4 acc[2][8] = {};
#pragma unroll
  for (int nf = 0; nf < 8; ++nf) {
    bf16x8 khi, klo;
    if (quad < 2) {
      split8(Kb + (size_t)(nf * 16 + m16) * QLD + quad * 8, khi, klo);
    } else {
#pragma unroll
      for (int j = 0; j < 8; ++j) { khi[j] = (__bf16)0.f; klo[j] = (__bf16)0.f; }
    }
#pragma unroll
    for (int mf = 0; mf < 2; ++mf) {
      acc[mf][nf] = __builtin_amdgcn_mfma_f32_16x16x32_bf16(qhi[mf], khi, acc[mf][nf], 0, 0, 0);
      acc[mf][nf] = __builtin_amdgcn_mfma_f32_16x16x32_bf16(qhi[mf], klo, acc[mf][nf], 0, 0, 0);
      acc[mf][nf] = __builtin_amdgcn_mfma_f32_16x16x32_bf16(qlo[mf], khi, acc[mf][nf], 0, 0, 0);
    }
  }

  const float scale = 0.25f;
#pragma unroll
  for (int mf = 0; mf < 2; ++mf)
#pragma unroll
    for (int reg = 0; reg < 4; ++reg) {
      float mx = -1e30f;
#pragma unroll
      for (int nf = 0; nf < 8; ++nf) mx = fmaxf(mx, acc[mf][nf][reg]);
#pragma unroll
      for (int off = 1; off < 16; off <<= 1) mx = fmaxf(mx, __shfl_xor(mx, off, 64));
      float sum = 0.f;
#pragma unroll
      for (int nf = 0; nf < 8; ++nf) {
        float e = __expf((acc[mf][nf][reg] - mx) * scale);
        acc[mf][nf][reg] = e;
        sum += e;
      }
#pragma unroll
      for (int off = 1; off < 16; off <<= 1) sum += __shfl_xor(sum, off, 64);
      float inv = 1.f / sum;
#pragma unroll
      for (int nf = 0; nf < 8; ++nf) acc[mf][nf][reg] *= inv;
    }

#pragma unroll
  for (int mf = 0; mf < 2; ++mf)
#pragma unroll
    for (int nf = 0; nf < 8; ++nf)
#pragma unroll
      for (int reg = 0; reg < 4; ++reg)
        Plds[wave][mf * 16 + quad * 4 + reg][nf * 16 + m16] = (__bf16)acc[mf][nf][reg];

  f32x4 oacc[2] = {};
#pragma unroll
  for (int kc = 0; kc < 4; ++kc) {
    bf16x8 pa0 = *(const bf16x8*)&Plds[wave][m16][kc * 32 + quad * 8];
    bf16x8 pa1 = *(const bf16x8*)&Plds[wave][16 + m16][kc * 32 + quad * 8];
    bf16x8 vhi, vlo;
#pragma unroll
    for (int j = 0; j < 8; ++j) {
      float x = Vb[(size_t)(kc * 32 + quad * 8 + j) * QLD + m16];
      __bf16 hh = (__bf16)x;
      vhi[j] = hh;
      vlo[j] = (__bf16)(x - (float)hh);
    }
    oacc[0] = __builtin_amdgcn_mfma_f32_16x16x32_bf16(pa0, vhi, oacc[0], 0, 0, 0);
    oacc[0] = __builtin_amdgcn_mfma_f32_16x16x32_bf16(pa0, vlo, oacc[0], 0, 0, 0);
    oacc[1] = __builtin_amdgcn_mfma_f32_16x16x32_bf16(pa1, vhi, oacc[1], 0, 0, 0);
    oacc[1] = __builtin_amdgcn_mfma_f32_16x16x32_bf16(pa1, vlo, oacc[1], 0, 0, 0);
  }

  __syncthreads();
#pragma unroll
  for (int mf = 0; mf < 2; ++mf)
#pragma unroll
    for (int reg = 0; reg < 4; ++reg) {
      int r = row0 + mf * 16 + quad * 4 + reg;
      Ob[(size_t)r * QLD + m16] = oacc[mf][reg];
    }
}

// ---------------- gating dot ----------------
__global__ __launch_bounds__(256) void sdot_kernel(
    const float* __restrict__ e, const float* __restrict__ x, float* __restrict__ s) {
  int r = blockIdx.x * 4 + (threadIdx.x >> 6);
  int lane = threadIdx.x & 63;
  const float* ep = e + (size_t)r * D_;
  const float* xp = x + (size_t)r * D_;
  float acc = ep[lane] * xp[lane] + ep[lane + 64] * xp[lane + 64];
#pragma unroll
  for (int off = 32; off; off >>= 1) acc += __shfl_down(acc, off, 64);
  if (lane == 0) {
    int t = r & (T_ - 1);
    int bn = r >> 7;
    int n = bn & (NA - 1);
    int b = bn >> 6;
    s[(size_t)b * NN + t * NA + n] = acc;
  }
}

// ---------------- edge scatter ----------------
__global__ __launch_bounds__(256) void scatter_kernel(
    const float* __restrict__ s, const int* __restrict__ ei,
    const float* __restrict__ ew, float* __restrict__ g) {
  int idx = blockIdx.x * 256 + threadIdx.x;
  if (idx >= B_ * E_) return;
  int b = idx >> 16;
  int e = idx & (E_ - 1);
  int src = ei[(size_t)b * 2 * E_ + e];
  int dst = ei[(size_t)b * 2 * E_ + E_ + e];
  float w = ew[(size_t)b * E_ + e];
  atomicAdd(&g[(size_t)b * NN + dst], w * s[(size_t)b * NN + src]);
}

// ---------------- partial sums for global mean/var ----------------
__global__ __launch_bounds__(256) void stats_partial(
    const float* __restrict__ g, float* __restrict__ st) {
  int i = blockIdx.x * 256 + threadIdx.x;
  float v = g[i];
  float sum = v, sq = v * v;
#pragma unroll
  for (int off = 32; off; off >>= 1) {
    sum += __shfl_down(sum, off, 64);
    sq += __shfl_down(sq, off, 64);
  }
  __shared__ float s1[4], s2[4];
  int w = threadIdx.x >> 6;
  if ((threadIdx.x & 63) == 0) { s1[w] = sum; s2[w] = sq; }
  __syncthreads();
  if (threadIdx.x == 0) {
    atomicAdd(&st[0], s1[0] + s1[1] + s1[2] + s1[3]);
    atomicAdd(&st[1], s2[0] + s2[1] + s2[2] + s2[3]);
  }
}

// ---------------- final (fp32 out) ----------------
__global__ __launch_bounds__(256) void final_kernel(
    const float* __restrict__ g, const float* __restrict__ st,
    const float* __restrict__ bng, const float* __restrict__ bnb,
    const float* __restrict__ lw, const float* __restrict__ lb,
    float* __restrict__ out) {
  int idx = blockIdx.x * 256 + threadIdx.x;
  if (idx >= NTOT * D_) return;
  int d = idx & (D_ - 1);
  int r = idx >> 7;
  int t = r & (T_ - 1);
  int bn = r >> 7;
  int n = bn & (NA - 1);
  int b = bn >> 6;
  const float invn = 1.f / (float)(B_ * NN);
  float m = st[0] * invn;
  float var = st[1] * invn - m * m;
  float rs = rsqrtf(var + EPS_);
  float gv = g[(size_t)b * NN + t * NA + n];
  float val = (gv - m) * rs * bng[0] + bnb[0];
  out[idx] = val * lw[d] + lb[d];
}

extern "C" void kernel_launch(void* const* d_in, const int* in_sizes, int n_in,
                              void* d_out, int out_size, void* d_ws, size_t ws_size,
                              hipStream_t stream) {
  const float* hist = (const float*)d_in[0];
  const int* eidx = (const int*)d_in[1];
  const float* ew = (const float*)d_in[2];
  const float* hw = (const float*)d_in[3];
  const float* hb = (const float*)d_in[4];
  const float* wq = (const float*)d_in[5];
  const float* bq = (const float*)d_in[6];
  const float* wk = (const float*)d_in[7];
  const float* bk = (const float*)d_in[8];
  const float* wv = (const float*)d_in[9];
  const float* bv = (const float*)d_in[10];
  const float* wo = (const float*)d_in[11];
  const float* bo = (const float*)d_in[12];
  const float* ln1g = (const float*)d_in[13];
  const float* ln1b = (const float*)d_in[14];
  const float* w1 = (const float*)d_in[15];
  const float* b1 = (const float*)d_in[16];
  const float* w2 = (const float*)d_in[17];
  const float* b2 = (const float*)d_in[18];
  const float* ln2g = (const float*)d_in[19];
  const float* ln2b = (const float*)d_in[20];
  const float* bng = (const float*)d_in[21];
  const float* bnb = (const float*)d_in[22];
  const float* lgw = (const float*)d_in[23];
  const float* lgb = (const float*)d_in[24];
  float* out = (float*)d_out;

  // ws layout (~181 MB of 268): bx 0, be 1, h1 2, qkv 3..6 (ffmid 3..7 overlaps),
  // split-K partials 7..11, then bs/bg/bst/pbias/weights.
  float* ws = (float*)d_ws;
  const size_t NE = NE_;
  float* bx = ws + 0 * NE;
  float* be = ws + 1 * NE;
  float* h1 = ws + 2 * NE;
  float* qkv = ws + 3 * NE;   // 3NE, [row][384]
  float* ffmid = ws + 3 * NE; // 4NE, overlaps dead qkv
  float* pk_ = ws + 7 * NE;   // 4NE partials
  float* bs_ = ws + 11 * NE;
  float* bg_ = bs_ + NTOT;
  float* bst = bg_ + NTOT;
  float* pbias = bst + 2;
  const int LW = 196608;
  __bf16* whiB = (__bf16*)(pbias + L_ * QLD);
  __bf16* wloB = whiB + (size_t)L_ * LW;

  convert_weights<<<(L_ * LW + 255) / 256, 256, 0, stream>>>(
      wq, wk, wv, wo, w1, w2, whiB, wloB);
  bias_pack<<<(L_ * QLD + 255) / 256, 256, 0, stream>>>(bq, bk, bv, pbias);
  embed_kernel<<<(NTOT * D_) / 256, 256, 0, stream>>>(hist, hw, hb, bx, be);

  for (int l = 0; l < L_; ++l) {
    const __bf16* hiL = whiB + (size_t)l * LW;
    const __bf16* loL = wloB + (size_t)l * LW;
    // QKV: one N=384 GEMM into packed [row][384]
    gemm_big<0, 128><<<dim3(3, NTOT / 128), 256, 0, stream>>>(
        be, 128, hiL, loL, pbias + l * QLD, qkv, QLD);
    attn_mfma<<<B_ * NA * H_, 256, 0, stream>>>(qkv);
    // O-proj + residual(be) + LN1 -> h1
    gemm_ln<128><<<dim3(1, NTOT / 64), 256, 0, stream>>>(
        qkv + 256, QLD, hiL + 49152, loL + 49152, bo + l * D_, be,
        ln1g + l * D_, ln1b + l * D_, h1);
    // FF1 (relu) -> ffmid
    gemm_big<1, 128><<<dim3(4, NTOT / 128), 256, 0, stream>>>(
        h1, 128, hiL + 65536, loL + 65536, b1 + l * DFF, ffmid, 512);
    // FF2 split-K (4 chunks) -> partials, then reduce + resid + LN2 -> be
    gemm_pk<<<dim3(4, NTOT / 64), 256, 0, stream>>>(
        ffmid, hiL + 131072, loL + 131072, pk_);
    reduce_ln4<<<NTOT, 128, 0, stream>>>(
        pk_, b2 + l * D_, h1, ln2g + l * D_, ln2b + l * D_, be);
  }

  sdot_kernel<<<NTOT / 4, 256, 0, stream>>>(be, bx, bs_);
  hipMemsetAsync(bg_, 0, ((size_t)B_ * NN + 2) * sizeof(float), stream);
  scatter_kernel<<<(B_ * E_) / 256, 256, 0, stream>>>(bs_, eidx, ew, bg_);
  stats_partial<<<(B_ * NN) / 256, 256, 0, stream>>>(bg_, bst);
  final_kernel<<<(NTOT * D_) / 256, 256, 0, stream>>>(bg_, bst, bng, bnb, lgw, lgb, out);
}

// Round 12
// 555.419 us; speedup vs baseline: 1.4016x; 1.0914x over previous
//
#include <hip/hip_runtime.h>
#include <hip/hip_bf16.h>
#include <math.h>

#define EPS_ 1e-5f
constexpr int B_ = 4, NA = 64, T_ = 128, D_ = 128, H_ = 8, L_ = 3, DFF = 512, E_ = 65536;
constexpr int DH = D_ / H_;        // 16
constexpr int NN = T_ * NA;        // 8192
constexpr int NTOT = B_ * NA * T_; // 32768
constexpr int QLD = 384;           // packed QKV row stride
constexpr size_t NE_ = (size_t)NTOT * D_;

typedef __bf16 bf16x8 __attribute__((ext_vector_type(8)));
typedef float f32x4 __attribute__((ext_vector_type(4)));

// ---------------- embed: x = hist@W + b ; e = x + posenc ----------------
__global__ __launch_bounds__(256) void embed_kernel(
    const float* __restrict__ hist, const float* __restrict__ w,
    const float* __restrict__ b, float* __restrict__ x, float* __restrict__ e) {
  int idx = blockIdx.x * 256 + threadIdx.x;
  if (idx >= NTOT * D_) return;
  int d = idx & (D_ - 1);
  int r = idx >> 7;
  int t = r & (T_ - 1);
  const float* hp = hist + (size_t)r * 3;
  float acc = b[d];
  acc += hp[0] * w[0 * D_ + d];
  acc += hp[1] * w[1 * D_ + d];
  acc += hp[2] * w[2 * D_ + d];
  x[idx] = acc;
  int p = d >> 1;
  float ang = (float)t * expf(-logf(10000.f) * (2.f * (float)p) / (float)D_);
  float pe = (d & 1) ? cosf(ang) : sinf(ang);
  e[idx] = acc + pe;
}

// ---------------- weight split into FRAGMENT-LINEAR bf16 hi/lo ----------------
// (n,k) -> nt=n>>4, kt=k>>5, lane=((k>>3)&3)*16+(n&15), j=k&7;
// dst = ((nt*(K/32)+kt)*64+lane)*8+j  => wave B-frag load = base+lane*16B (coalesced).
__global__ __launch_bounds__(256) void convert_weights(
    const float* __restrict__ wq, const float* __restrict__ wk,
    const float* __restrict__ wv, const float* __restrict__ wo,
    const float* __restrict__ w1, const float* __restrict__ w2,
    __bf16* __restrict__ hi, __bf16* __restrict__ lo) {
  const int LW = 196608;
  int idx = blockIdx.x * 256 + threadIdx.x;
  if (idx >= L_ * LW) return;
  int l = idx / LW;
  int rem = idx - l * LW;
  float src;
  int n, k, K, segoff;
  if (rem < 49152) { // qkv
    n = rem >> 7; k = rem & 127; K = 128; segoff = 0;
    int which = n >> 7, nl = n & 127;
    const float* W = (which == 0) ? wq : (which == 1) ? wk : wv;
    src = W[(size_t)l * 16384 + k * 128 + nl];
  } else if (rem < 65536) { // wo
    int r2 = rem - 49152;
    n = r2 >> 7; k = r2 & 127; K = 128; segoff = 49152;
    src = wo[(size_t)l * 16384 + k * 128 + n];
  } else if (rem < 131072) { // w1
    int r2 = rem - 65536;
    n = r2 >> 7; k = r2 & 127; K = 128; segoff = 65536;
    src = w1[(size_t)l * 65536 + k * 512 + n];
  } else { // w2
    int r2 = rem - 131072;
    n = r2 >> 9; k = r2 & 511; K = 512; segoff = 131072;
    src = w2[(size_t)l * 65536 + k * 128 + n];
  }
  int nt = n >> 4, kt = k >> 5;
  int lane = ((k >> 3) & 3) * 16 + (n & 15);
  int j = k & 7;
  int dst = l * LW + segoff + ((nt * (K / 32) + kt) * 64 + lane) * 8 + j;
  __bf16 h = (__bf16)src;
  hi[dst] = h;
  lo[dst] = (__bf16)(src - (float)h);
}

// ---------------- pack QKV biases ----------------
__global__ __launch_bounds__(256) void bias_pack(
    const float* __restrict__ bq, const float* __restrict__ bk,
    const float* __restrict__ bv, float* __restrict__ pb) {
  int idx = blockIdx.x * 256 + threadIdx.x;
  if (idx >= L_ * QLD) return;
  int l = idx / QLD, n = idx - l * QLD;
  int which = n >> 7, nl = n & 127;
  const float* src = (which == 0) ? bq : (which == 1) ? bk : bv;
  pb[idx] = src[l * 128 + nl];
}

__device__ __forceinline__ void split8(const float* __restrict__ p,
                                       bf16x8& hi, bf16x8& lo) {
  float4 x0 = *(const float4*)p;
  float4 x1 = *(const float4*)(p + 4);
  float xv[8] = {x0.x, x0.y, x0.z, x0.w, x1.x, x1.y, x1.z, x1.w};
#pragma unroll
  for (int j = 0; j < 8; ++j) {
    __bf16 h = (__bf16)xv[j];
    hi[j] = h;
    lo[j] = (__bf16)(xv[j] - (float)h);
  }
}

// ---------------- MFMA GEMM, 128x128 tile (wave 64x64), frag-linear W ----------------
template <int EPI, int K>
__global__ __launch_bounds__(256) void gemm_big(
    const float* __restrict__ A, int lda,
    const __bf16* __restrict__ Whi, const __bf16* __restrict__ Wlo,
    const float* __restrict__ bias,
    float* __restrict__ C, int ldc) {
  const int wave = threadIdx.x >> 6;
  const int lane = threadIdx.x & 63;
  const int m16 = lane & 15;
  const int quad = lane >> 4;
  const int wrow = wave >> 1, wcol = wave & 1;
  const int row0 = blockIdx.y * 128 + wrow * 64;
  const int col0 = blockIdx.x * 128 + wcol * 64;
  const int ctb = col0 >> 4;

  f32x4 acc[4][4] = {};
#pragma unroll
  for (int k0 = 0; k0 < K; k0 += 32) {
    bf16x8 ahi[4], alo[4];
#pragma unroll
    for (int mf = 0; mf < 4; ++mf)
      split8(A + (size_t)(row0 + mf * 16 + m16) * lda + k0 + quad * 8, ahi[mf], alo[mf]);
    bf16x8 bhi[4], blo[4];
#pragma unroll
    for (int nf = 0; nf < 4; ++nf) {
      size_t off = ((size_t)(ctb + nf) * (K / 32) + (k0 >> 5)) * 512 + lane * 8;
      bhi[nf] = *(const bf16x8*)(Whi + off);
      blo[nf] = *(const bf16x8*)(Wlo + off);
    }
#pragma unroll
    for (int mf = 0; mf < 4; ++mf)
#pragma unroll
      for (int nf = 0; nf < 4; ++nf) {
        acc[mf][nf] = __builtin_amdgcn_mfma_f32_16x16x32_bf16(ahi[mf], bhi[nf], acc[mf][nf], 0, 0, 0);
        acc[mf][nf] = __builtin_amdgcn_mfma_f32_16x16x32_bf16(ahi[mf], blo[nf], acc[mf][nf], 0, 0, 0);
        acc[mf][nf] = __builtin_amdgcn_mfma_f32_16x16x32_bf16(alo[mf], bhi[nf], acc[mf][nf], 0, 0, 0);
      }
  }
#pragma unroll
  for (int mf = 0; mf < 4; ++mf)
#pragma unroll
    for (int nf = 0; nf < 4; ++nf) {
      int c = col0 + nf * 16 + m16;
      float bj = bias[c];
#pragma unroll
      for (int reg = 0; reg < 4; ++reg) {
        int r = row0 + mf * 16 + quad * 4 + reg;
        float v = acc[mf][nf][reg] + bj;
        if (EPI == 1) v = fmaxf(v, 0.f);
        C[(size_t)r * ldc + c] = v;
      }
    }
}

// ---------------- GEMM + bias + resid + LayerNorm; block 64x128, K=128 (O-proj) ----------------
template <int K>
__global__ __launch_bounds__(256) void gemm_ln(
    const float* __restrict__ A, int lda,
    const __bf16* __restrict__ Whi, const __bf16* __restrict__ Wlo,
    const float* __restrict__ bias, const float* __restrict__ resid,
    const float* __restrict__ lng, const float* __restrict__ lnb,
    float* __restrict__ C) {
  const int wave = threadIdx.x >> 6;
  const int lane = threadIdx.x & 63;
  const int m16 = lane & 15;
  const int quad = lane >> 4;
  const int wrow = wave >> 1, wcol = wave & 1;
  const int row0 = blockIdx.y * 64 + wrow * 32;
  const int col0 = wcol * 64;
  const int ctb = wcol * 4;

  f32x4 acc[2][4] = {};
#pragma unroll
  for (int k0 = 0; k0 < K; k0 += 32) {
    bf16x8 ahi[2], alo[2];
#pragma unroll
    for (int mf = 0; mf < 2; ++mf)
      split8(A + (size_t)(row0 + mf * 16 + m16) * lda + k0 + quad * 8, ahi[mf], alo[mf]);
    bf16x8 bhi[4], blo[4];
#pragma unroll
    for (int nf = 0; nf < 4; ++nf) {
      size_t off = ((size_t)(ctb + nf) * (K / 32) + (k0 >> 5)) * 512 + lane * 8;
      bhi[nf] = *(const bf16x8*)(Whi + off);
      blo[nf] = *(const bf16x8*)(Wlo + off);
    }
#pragma unroll
    for (int mf = 0; mf < 2; ++mf)
#pragma unroll
      for (int nf = 0; nf < 4; ++nf) {
        acc[mf][nf] = __builtin_amdgcn_mfma_f32_16x16x32_bf16(ahi[mf], bhi[nf], acc[mf][nf], 0, 0, 0);
        acc[mf][nf] = __builtin_amdgcn_mfma_f32_16x16x32_bf16(ahi[mf], blo[nf], acc[mf][nf], 0, 0, 0);
        acc[mf][nf] = __builtin_amdgcn_mfma_f32_16x16x32_bf16(alo[mf], bhi[nf], acc[mf][nf], 0, 0, 0);
      }
  }
  __shared__ float rs[64][2], rq[64][2];
#pragma unroll
  for (int mf = 0; mf < 2; ++mf)
#pragma unroll
    for (int reg = 0; reg < 4; ++reg) {
      int lr = wrow * 32 + mf * 16 + quad * 4 + reg;
      int gr = blockIdx.y * 64 + lr;
      float s = 0.f, qq = 0.f;
#pragma unroll
      for (int nf = 0; nf < 4; ++nf) {
        int c = col0 + nf * 16 + m16;
        float v = acc[mf][nf][reg] + bias[c] + resid[(size_t)gr * 128 + c];
        acc[mf][nf][reg] = v;
        s += v;
        qq += v * v;
      }
#pragma unroll
      for (int off = 1; off < 16; off <<= 1) {
        s += __shfl_xor(s, off, 64);
        qq += __shfl_xor(qq, off, 64);
      }
      if (m16 == 0) { rs[lr][wcol] = s; rq[lr][wcol] = qq; }
    }
  __syncthreads();
#pragma unroll
  for (int mf = 0; mf < 2; ++mf)
#pragma unroll
    for (int reg = 0; reg < 4; ++reg) {
      int lr = wrow * 32 + mf * 16 + quad * 4 + reg;
      int gr = blockIdx.y * 64 + lr;
      float mean = (rs[lr][0] + rs[lr][1]) * (1.f / 128.f);
      float var = (rq[lr][0] + rq[lr][1]) * (1.f / 128.f) - mean * mean;
      float rstd = rsqrtf(var + EPS_);
#pragma unroll
      for (int nf = 0; nf < 4; ++nf) {
        int c = col0 + nf * 16 + m16;
        C[(size_t)gr * 128 + c] = (acc[mf][nf][reg] - mean) * rstd * lng[c] + lnb[c];
      }
    }
}

// ---------------- FF2 + LN, K=512, LDS-staged A (coalesced), frag-linear W ----------------
// Block 64 rows x 128 cols; A staged in 4 chunks of 64x128 fp32 ([64][129] pad).
__global__ __launch_bounds__(256) void ff2_ln(
    const float* __restrict__ A, // ffmid [M][512]
    const __bf16* __restrict__ Whi, const __bf16* __restrict__ Wlo,
    const float* __restrict__ bias, const float* __restrict__ resid,
    const float* __restrict__ lng, const float* __restrict__ lnb,
    float* __restrict__ C) {
  const int wave = threadIdx.x >> 6;
  const int lane = threadIdx.x & 63;
  const int m16 = lane & 15;
  const int quad = lane >> 4;
  const int wrow = wave >> 1, wcol = wave & 1;
  const int grow0 = blockIdx.y * 64;
  const int lrow0 = wrow * 32;
  const int col0 = wcol * 64;
  const int ctb = wcol * 4;

  __shared__ float As[64][129]; // 33 KB, +1 pad -> linear bank spread

  f32x4 acc[2][4] = {};
  for (int kc = 0; kc < 4; ++kc) {
    if (kc) __syncthreads(); // prior-stage reads done
    // stage A chunk: 64 rows x 128 floats, coalesced (32 thr x 16B = 512B bursts)
#pragma unroll
    for (int u = 0; u < 8; ++u) {
      int unit = threadIdx.x + u * 256; // 2048 float4 units
      int r = unit >> 5, c4 = unit & 31;
      float4 v = *(const float4*)(A + (size_t)(grow0 + r) * 512 + kc * 128 + c4 * 4);
      As[r][c4 * 4 + 0] = v.x;
      As[r][c4 * 4 + 1] = v.y;
      As[r][c4 * 4 + 2] = v.z;
      As[r][c4 * 4 + 3] = v.w;
    }
    __syncthreads();
#pragma unroll
    for (int kt = 0; kt < 4; ++kt) {
      bf16x8 ahi[2], alo[2];
#pragma unroll
      for (int mf = 0; mf < 2; ++mf)
        split8(&As[lrow0 + mf * 16 + m16][kt * 32 + quad * 8], ahi[mf], alo[mf]);
      bf16x8 bhi[4], blo[4];
#pragma unroll
      for (int nf = 0; nf < 4; ++nf) {
        size_t off = ((size_t)(ctb + nf) * 16 + (kc * 4 + kt)) * 512 + lane * 8;
        bhi[nf] = *(const bf16x8*)(Whi + off);
        blo[nf] = *(const bf16x8*)(Wlo + off);
      }
#pragma unroll
      for (int mf = 0; mf < 2; ++mf)
#pragma unroll
        for (int nf = 0; nf < 4; ++nf) {
          acc[mf][nf] = __builtin_amdgcn_mfma_f32_16x16x32_bf16(ahi[mf], bhi[nf], acc[mf][nf], 0, 0, 0);
          acc[mf][nf] = __builtin_amdgcn_mfma_f32_16x16x32_bf16(ahi[mf], blo[nf], acc[mf][nf], 0, 0, 0);
          acc[mf][nf] = __builtin_amdgcn_mfma_f32_16x16x32_bf16(alo[mf], bhi[nf], acc[mf][nf], 0, 0, 0);
        }
    }
  }
  __shared__ float rs[64][2], rq[64][2];
#pragma unroll
  for (int mf = 0; mf < 2; ++mf)
#pragma unroll
    for (int reg = 0; reg < 4; ++reg) {
      int lr = lrow0 + mf * 16 + quad * 4 + reg;
      int gr = grow0 + lr;
      float s = 0.f, qq = 0.f;
#pragma unroll
      for (int nf = 0; nf < 4; ++nf) {
        int c = col0 + nf * 16 + m16;
        float v = acc[mf][nf][reg] + bias[c] + resid[(size_t)gr * 128 + c];
        acc[mf][nf][reg] = v;
        s += v;
        qq += v * v;
      }
#pragma unroll
      for (int off = 1; off < 16; off <<= 1) {
        s += __shfl_xor(s, off, 64);
        qq += __shfl_xor(qq, off, 64);
      }
      if (m16 == 0) { rs[lr][wcol] = s; rq[lr][wcol] = qq; }
    }
  __syncthreads();
#pragma unroll
  for (int mf = 0; mf < 2; ++mf)
#pragma unroll
    for (int reg = 0; reg < 4; ++reg) {
      int lr = lrow0 + mf * 16 + quad * 4 + reg;
      int gr = grow0 + lr;
      float mean = (rs[lr][0] + rs[lr][1]) * (1.f / 128.f);
      float var = (rq[lr][0] + rq[lr][1]) * (1.f / 128.f) - mean * mean;
      float rstd = rsqrtf(var + EPS_);
#pragma unroll
      for (int nf = 0; nf < 4; ++nf) {
        int c = col0 + nf * 16 + m16;
        C[(size_t)gr * 128 + c] = (acc[mf][nf][reg] - mean) * rstd * lng[c] + lnb[c];
      }
    }
}

// ---------------- MFMA attention on packed QKV; O overwrites the V slice ----------------
__global__ __launch_bounds__(256) void attn_mfma(float* __restrict__ qkv) {
  const int h = blockIdx.x & (H_ - 1);
  const int bn = blockIdx.x >> 3;
  const int wave = threadIdx.x >> 6;
  const int lane = threadIdx.x & 63;
  const int m16 = lane & 15;
  const int quad = lane >> 4;
  const int row0 = wave * 32;
  const float* Qb = qkv + (size_t)bn * T_ * QLD + h * DH;
  const float* Kb = Qb + 128;
  const float* Vb = Qb + 256;
  float* Ob = (float*)Vb;

  __shared__ __bf16 Plds[4][32][136];

  bf16x8 qhi[2], qlo[2];
#pragma unroll
  for (int mf = 0; mf < 2; ++mf) {
    if (quad < 2) {
      split8(Qb + (size_t)(row0 + mf * 16 + m16) * QLD + quad * 8, qhi[mf], qlo[mf]);
    } else {
#pragma unroll
      for (int j = 0; j < 8; ++j) { qhi[mf][j] = (__bf16)0.f; qlo[mf][j] = (__bf16)0.f; }
    }
  }

  f32x4 acc[2][8] = {};
#pragma unroll
  for (int nf = 0; nf < 8; ++nf) {
    bf16x8 khi, klo;
    if (quad < 2) {
      split8(Kb + (size_t)(nf * 16 + m16) * QLD + quad * 8, khi, klo);
    } else {
#pragma unroll
      for (int j = 0; j < 8; ++j) { khi[j] = (__bf16)0.f; klo[j] = (__bf16)0.f; }
    }
#pragma unroll
    for (int mf = 0; mf < 2; ++mf) {
      acc[mf][nf] = __builtin_amdgcn_mfma_f32_16x16x32_bf16(qhi[mf], khi, acc[mf][nf], 0, 0, 0);
      acc[mf][nf] = __builtin_amdgcn_mfma_f32_16x16x32_bf16(qhi[mf], klo, acc[mf][nf], 0, 0, 0);
      acc[mf][nf] = __builtin_amdgcn_mfma_f32_16x16x32_bf16(qlo[mf], khi, acc[mf][nf], 0, 0, 0);
    }
  }

  const float scale = 0.25f;
#pragma unroll
  for (int mf = 0; mf < 2; ++mf)
#pragma unroll
    for (int reg = 0; reg < 4; ++reg) {
      float mx = -1e30f;
#pragma unroll
      for (int nf = 0; nf < 8; ++nf) mx = fmaxf(mx, acc[mf][nf][reg]);
#pragma unroll
      for (int off = 1; off < 16; off <<= 1) mx = fmaxf(mx, __shfl_xor(mx, off, 64));
      float sum = 0.f;
#pragma unroll
      for (int nf = 0; nf < 8; ++nf) {
        float e = __expf((acc[mf][nf][reg] - mx) * scale);
        acc[mf][nf][reg] = e;
        sum += e;
      }
#pragma unroll
      for (int off = 1; off < 16; off <<= 1) sum += __shfl_xor(sum, off, 64);
      float inv = 1.f / sum;
#pragma unroll
      for (int nf = 0; nf < 8; ++nf) acc[mf][nf][reg] *= inv;
    }

#pragma unroll
  for (int mf = 0; mf < 2; ++mf)
#pragma unroll
    for (int nf = 0; nf < 8; ++nf)
#pragma unroll
      for (int reg = 0; reg < 4; ++reg)
        Plds[wave][mf * 16 + quad * 4 + reg][nf * 16 + m16] = (__bf16)acc[mf][nf][reg];

  f32x4 oacc[2] = {};
#pragma unroll
  for (int kc = 0; kc < 4; ++kc) {
    bf16x8 pa0 = *(const bf16x8*)&Plds[wave][m16][kc * 32 + quad * 8];
    bf16x8 pa1 = *(const bf16x8*)&Plds[wave][16 + m16][kc * 32 + quad * 8];
    bf16x8 vhi, vlo;
#pragma unroll
    for (int j = 0; j < 8; ++j) {
      float x = Vb[(size_t)(kc * 32 + quad * 8 + j) * QLD + m16];
      __bf16 hh = (__bf16)x;
      vhi[j] = hh;
      vlo[j] = (__bf16)(x - (float)hh);
    }
    oacc[0] = __builtin_amdgcn_mfma_f32_16x16x32_bf16(pa0, vhi, oacc[0], 0, 0, 0);
    oacc[0] = __builtin_amdgcn_mfma_f32_16x16x32_bf16(pa0, vlo, oacc[0], 0, 0, 0);
    oacc[1] = __builtin_amdgcn_mfma_f32_16x16x32_bf16(pa1, vhi, oacc[1], 0, 0, 0);
    oacc[1] = __builtin_amdgcn_mfma_f32_16x16x32_bf16(pa1, vlo, oacc[1], 0, 0, 0);
  }

  __syncthreads();
#pragma unroll
  for (int mf = 0; mf < 2; ++mf)
#pragma unroll
    for (int reg = 0; reg < 4; ++reg) {
      int r = row0 + mf * 16 + quad * 4 + reg;
      Ob[(size_t)r * QLD + m16] = oacc[mf][reg];
    }
}

// ---------------- gating dot ----------------
__global__ __launch_bounds__(256) void sdot_kernel(
    const float* __restrict__ e, const float* __restrict__ x, float* __restrict__ s) {
  int r = blockIdx.x * 4 + (threadIdx.x >> 6);
  int lane = threadIdx.x & 63;
  const float* ep = e + (size_t)r * D_;
  const float* xp = x + (size_t)r * D_;
  float acc = ep[lane] * xp[lane] + ep[lane + 64] * xp[lane + 64];
#pragma unroll
  for (int off = 32; off; off >>= 1) acc += __shfl_down(acc, off, 64);
  if (lane == 0) {
    int t = r & (T_ - 1);
    int bn = r >> 7;
    int n = bn & (NA - 1);
    int b = bn >> 6;
    s[(size_t)b * NN + t * NA + n] = acc;
  }
}

// ---------------- edge scatter ----------------
__global__ __launch_bounds__(256) void scatter_kernel(
    const float* __restrict__ s, const int* __restrict__ ei,
    const float* __restrict__ ew, float* __restrict__ g) {
  int idx = blockIdx.x * 256 + threadIdx.x;
  if (idx >= B_ * E_) return;
  int b = idx >> 16;
  int e = idx & (E_ - 1);
  int src = ei[(size_t)b * 2 * E_ + e];
  int dst = ei[(size_t)b * 2 * E_ + E_ + e];
  float w = ew[(size_t)b * E_ + e];
  atomicAdd(&g[(size_t)b * NN + dst], w * s[(size_t)b * NN + src]);
}

// ---------------- partial sums for global mean/var ----------------
__global__ __launch_bounds__(256) void stats_partial(
    const float* __restrict__ g, float* __restrict__ st) {
  int i = blockIdx.x * 256 + threadIdx.x;
  float v = g[i];
  float sum = v, sq = v * v;
#pragma unroll
  for (int off = 32; off; off >>= 1) {
    sum += __shfl_down(sum, off, 64);
    sq += __shfl_down(sq, off, 64);
  }
  __shared__ float s1[4], s2[4];
  int w = threadIdx.x >> 6;
  if ((threadIdx.x & 63) == 0) { s1[w] = sum; s2[w] = sq; }
  __syncthreads();
  if (threadIdx.x == 0) {
    atomicAdd(&st[0], s1[0] + s1[1] + s1[2] + s1[3]);
    atomicAdd(&st[1], s2[0] + s2[1] + s2[2] + s2[3]);
  }
}

// ---------------- final (fp32 out) ----------------
__global__ __launch_bounds__(256) void final_kernel(
    const float* __restrict__ g, const float* __restrict__ st,
    const float* __restrict__ bng, const float* __restrict__ bnb,
    const float* __restrict__ lw, const float* __restrict__ lb,
    float* __restrict__ out) {
  int idx = blockIdx.x * 256 + threadIdx.x;
  if (idx >= NTOT * D_) return;
  int d = idx & (D_ - 1);
  int r = idx >> 7;
  int t = r & (T_ - 1);
  int bn = r >> 7;
  int n = bn & (NA - 1);
  int b = bn >> 6;
  const float invn = 1.f / (float)(B_ * NN);
  float m = st[0] * invn;
  float var = st[1] * invn - m * m;
  float rs = rsqrtf(var + EPS_);
  float gv = g[(size_t)b * NN + t * NA + n];
  float val = (gv - m) * rs * bng[0] + bnb[0];
  out[idx] = val * lw[d] + lb[d];
}

extern "C" void kernel_launch(void* const* d_in, const int* in_sizes, int n_in,
                              void* d_out, int out_size, void* d_ws, size_t ws_size,
                              hipStream_t stream) {
  const float* hist = (const float*)d_in[0];
  const int* eidx = (const int*)d_in[1];
  const float* ew = (const float*)d_in[2];
  const float* hw = (const float*)d_in[3];
  const float* hb = (const float*)d_in[4];
  const float* wq = (const float*)d_in[5];
  const float* bq = (const float*)d_in[6];
  const float* wk = (const float*)d_in[7];
  const float* bk = (const float*)d_in[8];
  const float* wv = (const float*)d_in[9];
  const float* bv = (const float*)d_in[10];
  const float* wo = (const float*)d_in[11];
  const float* bo = (const float*)d_in[12];
  const float* ln1g = (const float*)d_in[13];
  const float* ln1b = (const float*)d_in[14];
  const float* w1 = (const float*)d_in[15];
  const float* b1 = (const float*)d_in[16];
  const float* w2 = (const float*)d_in[17];
  const float* b2 = (const float*)d_in[18];
  const float* ln2g = (const float*)d_in[19];
  const float* ln2b = (const float*)d_in[20];
  const float* bng = (const float*)d_in[21];
  const float* bnb = (const float*)d_in[22];
  const float* lgw = (const float*)d_in[23];
  const float* lgb = (const float*)d_in[24];
  float* out = (float*)d_out;

  float* ws = (float*)d_ws;
  const size_t NE = NE_;
  float* bx = ws + 0 * NE;
  float* be = ws + 1 * NE;
  float* h1 = ws + 2 * NE;
  float* qkv = ws + 3 * NE;   // 3NE, [row][384]
  float* ffmid = ws + 3 * NE; // 4NE, overlaps dead qkv
  float* bs_ = ws + 7 * NE;
  float* bg_ = bs_ + NTOT;
  float* bst = bg_ + NTOT;
  float* pbias = bst + 2;
  const int LW = 196608;
  __bf16* whiB = (__bf16*)(pbias + L_ * QLD);
  __bf16* wloB = whiB + (size_t)L_ * LW;

  convert_weights<<<(L_ * LW + 255) / 256, 256, 0, stream>>>(
      wq, wk, wv, wo, w1, w2, whiB, wloB);
  bias_pack<<<(L_ * QLD + 255) / 256, 256, 0, stream>>>(bq, bk, bv, pbias);
  embed_kernel<<<(NTOT * D_) / 256, 256, 0, stream>>>(hist, hw, hb, bx, be);

  for (int l = 0; l < L_; ++l) {
    const __bf16* hiL = whiB + (size_t)l * LW;
    const __bf16* loL = wloB + (size_t)l * LW;
    gemm_big<0, 128><<<dim3(3, NTOT / 128), 256, 0, stream>>>(
        be, 128, hiL, loL, pbias + l * QLD, qkv, QLD);
    attn_mfma<<<B_ * NA * H_, 256, 0, stream>>>(qkv);
    gemm_ln<128><<<dim3(1, NTOT / 64), 256, 0, stream>>>(
        qkv + 256, QLD, hiL + 49152, loL + 49152, bo + l * D_, be,
        ln1g + l * D_, ln1b + l * D_, h1);
    gemm_big<1, 128><<<dim3(4, NTOT / 128), 256, 0, stream>>>(
        h1, 128, hiL + 65536, loL + 65536, b1 + l * DFF, ffmid, 512);
    ff2_ln<<<dim3(1, NTOT / 64), 256, 0, stream>>>(
        ffmid, hiL + 131072, loL + 131072, b2 + l * D_, h1,
        ln2g + l * D_, ln2b + l * D_, be);
  }

  sdot_kernel<<<NTOT / 4, 256, 0, stream>>>(be, bx, bs_);
  hipMemsetAsync(bg_, 0, ((size_t)B_ * NN + 2) * sizeof(float), stream);
  scatter_kernel<<<(B_ * E_) / 256, 256, 0, stream>>>(bs_, eidx, ew, bg_);
  stats_partial<<<(B_ * NN) / 256, 256, 0, stream>>>(bg_, bst);
  final_kernel<<<(NTOT * D_) / 256, 256, 0, stream>>>(bg_, bst, bng, bnb, lgw, lgb, out);
}